// Round 6
// baseline (405.120 us; speedup 1.0000x reference)
//
#include <hip/hip_runtime.h>
#include <cstdint>
#include <cstddef>

#define N_TOT   147456      // 9*128*128
#define K_PRE   6000
#define K_POST  300
#define CAP     32768       // candidate cap (expected ~9.2K)
#define MW      188         // 6016 bits per mask row -> 188 u32 words
#define ROWS_PAD 6144       // 24*256 (scan prefetch range)
#define CH      256         // scan rows per chunk
#define NCH     24          // 24*256 = 6144
#define CT      128         // mask columns per tile
#define ROWB    24
#define COLB    47          // ceil(6000/128)
#define NTILE   (ROWB*COLB) // 1128 mask tiles
#define G       16          // candidates ranked per block
#define NBLK    576         // mega grid; __launch_bounds__(256,4) => capacity 1024, all resident
#define HBLK    144         // work blocks for hist/findbin (4 anchors/thread)

// workspace offsets (256-aligned)
#define OFF_KEYS 0u
#define OFF_CAND 589824u
#define OFF_P    851968u
#define OFF_YK   948224u
#define OFF_OP   996352u
#define OFF_Q    1092608u
#define OFF_BND  1188864u
#define OFF_MASK 1212928u   // + ROWS_PAD*MW*4 (+256 slack) = 5.83 MB total

__constant__ float c_sizes[9] = {4.f,8.f,12.f,16.f,24.f,32.f,48.f,64.f,96.f};

// Zero-initialized module globals. g_hist/g_cnt re-zeroed by the scan phase
// each run. g_bar is MONOTONIC (never reset): barrier i's target for a run is
// (ticket/NBLK+1)*NBLK, so graph replays compose without any reset hazard.
__device__ uint32_t g_hist[4096];
__device__ uint32_t g_cnt;
__device__ uint32_t g_bar[8];

// Hand-rolled grid barrier: device-scope atomics + agent fences (guide §6 G16).
// vs cg::grid_group::sync() (round 1: ~65us/sync), this is the minimal HW
// mechanism: release fence -> ticket -> spin on agent-scope load -> acquire
// fence. Watchdog breaks a dead spin so a failure is a wrong answer, not a hang.
__device__ __forceinline__ void gridBarrier(int i) {
    __syncthreads();
    if (threadIdx.x == 0) {
        __threadfence();                                 // release (L2 wb)
        uint32_t ticket = atomicAdd(&g_bar[i], 1u);
        uint32_t target = (ticket / NBLK + 1u) * NBLK;
        uint32_t tries = 0;
        while (__hip_atomic_load(&g_bar[i], __ATOMIC_RELAXED,
                                 __HIP_MEMORY_SCOPE_AGENT) < target) {
            __builtin_amdgcn_s_sleep(2);
            if (++tries > (1u << 24)) break;             // fail loud, not hung
        }
        __threadfence();                                 // acquire (inv caches)
    }
    __syncthreads();
}

// Bit-exact replication of reference box math (anchor + delta, clip).
__device__ __forceinline__ void compute_box(int idx, const float* __restrict__ deltas,
                                            float& px1, float& py1, float& pw, float& ph) {
    int a   = idx >> 14;
    int rem = idx & 16383;
    int h   = rem >> 7;
    int w   = rem & 127;
    float s    = c_sizes[a];
    float half = s * 0.5f;
    const float4 d = *(const float4*)(deltas + (size_t)a * 65536 + (size_t)rem * 4);
    float b0 = (((float)h + 0.5f) - half) + d.x;
    float b1 = (((float)w + 0.5f) - half) + d.y;
    float b2 = s + d.z;
    float b3 = s + d.w;
    b0 = fmaxf(b0, 0.0f); b1 = fmaxf(b1, 0.0f);
    b2 = fmaxf(b2, 0.0f); b3 = fmaxf(b3, 0.0f);
    float x1 = b0, y1 = b1;
    float x2 = b0 + b2, y2 = b1 + b3;
    x1 = fminf(x1, 128.0f); y1 = fminf(y1, 128.0f);
    x2 = fminf(x2, 128.0f); y2 = fminf(y2, 128.0f);
    px1 = x1; py1 = y1; pw = x2 - x1; ph = y2 - y1;
}

__device__ __forceinline__ uint32_t waveReduceSum(uint32_t v) {
    #pragma unroll
    for (int o = 32; o > 0; o >>= 1) v += __shfl_xor(v, o, 64);
    return v;
}

// ============================================================================
// Single fused kernel: 6 phases, 5 hand-rolled grid barriers, one dispatch.
// Phase bodies are verbatim the round-5 verified kernels.
// ============================================================================
__global__ void __launch_bounds__(256, 4) mega(const float* __restrict__ scores,
                                               const float* __restrict__ deltas,
                                               float* __restrict__ out,
                                               char* __restrict__ ws) {
    __shared__ __align__(16) char smem[17664];

    uint32_t* keys = (uint32_t*)(ws + OFF_KEYS);
    uint64_t* cand = (uint64_t*)(ws + OFF_CAND);
    float4*   P    = (float4*)(ws + OFF_P);
    uint64_t* yk   = (uint64_t*)(ws + OFF_YK);
    float4*   OP   = (float4*)(ws + OFF_OP);
    float4*   Q    = (float4*)(ws + OFF_Q);
    float*    Bnd  = (float*)(ws + OFF_BND);
    uint32_t* mask = (uint32_t*)(ws + OFF_MASK);

    const int tid  = threadIdx.x;
    const int bid  = blockIdx.x;
    const int wave = tid >> 6, lane = tid & 63;

    // ---- phase 1: keys + histogram (4 anchors/thread, blocks 0..143) ----
    if (bid < HBLK) {
        uint32_t* lh = (uint32_t*)smem;
        for (int i = tid; i < 4096; i += 256) lh[i] = 0u;
        __syncthreads();
        int t4 = (bid * 256 + tid) * 4;
        float4 sc4 = *(const float4*)(scores + t4);
        uint32_t k4[4];
        #pragma unroll
        for (int e = 0; e < 4; e++) {
            int idx = t4 + e;
            float px1, py1, pw, ph;
            compute_box(idx, deltas, px1, py1, pw, ph);
            bool keep = (pw >= 3.0f) && (ph >= 3.0f);
            float sc = (&sc4.x)[e];
            uint32_t key = keep ? __float_as_uint(sc) : 0u;
            k4[e] = key;
            atomicAdd(&lh[key >> 20], 1u);
        }
        *(uint4*)(keys + t4) = make_uint4(k4[0], k4[1], k4[2], k4[3]);
        __syncthreads();
        for (int i = tid; i < 4096; i += 256) {
            uint32_t v = lh[i];
            if (v) atomicAdd(&g_hist[i], v);
        }
    }
    gridBarrier(0);

    // ---- phase 2: findbin (suffix scan) + block-ticket compact ----
    if (bid < HBLK) {
        uint32_t* lh   = (uint32_t*)smem;
        uint32_t* seg  = (uint32_t*)(smem + 16384);
        uint32_t* bshp = (uint32_t*)(smem + 16384 + 1024);
        uint32_t* lcnt = bshp + 1;
        uint32_t* lbas = bshp + 2;
        if (tid == 0) lcnt[0] = 0u;
        for (int i = tid; i < 4096; i += 256) lh[i] = g_hist[i];
        __syncthreads();
        uint32_t s = 0;
        #pragma unroll
        for (int q = 0; q < 16; q++) s += lh[tid * 16 + q];
        seg[tid] = s;
        __syncthreads();
        for (int off = 1; off < 256; off <<= 1) {
            uint32_t v = seg[tid];
            if (tid + off < 256) v += seg[tid + off];
            __syncthreads();
            seg[tid] = v;
            __syncthreads();
        }
        uint32_t St  = seg[tid];
        uint32_t St1 = (tid < 255) ? seg[tid + 1] : 0u;
        if (St >= K_PRE && St1 < K_PRE) {
            uint32_t c2 = St1;
            uint32_t bstar = 0u;
            for (int q = 15; q >= 0; q--) {
                c2 += lh[tid * 16 + q];
                if (c2 >= K_PRE) { bstar = (uint32_t)(tid * 16 + q); break; }
            }
            bshp[0] = bstar;
        }
        if (tid == 0 && seg[0] < K_PRE) bshp[0] = 0u;
        __syncthreads();
        uint32_t bstar = bshp[0];
        int t4 = (bid * 256 + tid) * 4;
        uint4 kk = *(const uint4*)(keys + t4);
        bool s0 = (kk.x >> 20) >= bstar;
        bool s1 = (kk.y >> 20) >= bstar;
        bool s2 = (kk.z >> 20) >= bstar;
        bool s3 = (kk.w >> 20) >= bstar;
        uint32_t nsel = (uint32_t)s0 + s1 + s2 + s3;
        uint32_t myoff = 0u;
        if (nsel) myoff = atomicAdd(lcnt, nsel);
        __syncthreads();
        if (tid == 0) lbas[0] = atomicAdd(&g_cnt, lcnt[0]);
        __syncthreads();
        uint32_t pos = lbas[0] + myoff;
        if (s0) { if (pos < CAP) cand[pos] = ((uint64_t)kk.x << 32) | (uint32_t)(~(uint32_t)(t4 + 0)); pos++; }
        if (s1) { if (pos < CAP) cand[pos] = ((uint64_t)kk.y << 32) | (uint32_t)(~(uint32_t)(t4 + 1)); pos++; }
        if (s2) { if (pos < CAP) cand[pos] = ((uint64_t)kk.z << 32) | (uint32_t)(~(uint32_t)(t4 + 2)); pos++; }
        if (s3) { if (pos < CAP) cand[pos] = ((uint64_t)kk.w << 32) | (uint32_t)(~(uint32_t)(t4 + 3)); }
    }
    gridBarrier(1);

    // ---- phase 3: rank-by-count over candidates -> P, yk ----
    {
        uint32_t (*part)[G] = (uint32_t (*)[G])smem;
        uint32_t C = g_cnt;
        if (C > CAP) C = CAP;
        uint32_t nGroups = (C + G - 1) / G;     // ~575 <= NBLK
        for (uint32_t g = bid; g < nGroups; g += NBLK) {
            uint32_t b = g * G;
            uint64_t m[G];
            uint32_t cnt[G];
            #pragma unroll
            for (int q = 0; q < G; q++) {
                m[q] = (b + q < C) ? cand[b + q] : ~0ull;
                cnt[q] = 0u;
            }
            for (uint32_t j0 = 0; j0 < C; j0 += 1024) {
                uint32_t ja = j0 + tid, jb = ja + 256, jc = ja + 512, jd = ja + 768;
                uint64_t ka = (ja < C) ? cand[ja] : 0ull;
                uint64_t kb = (jb < C) ? cand[jb] : 0ull;
                uint64_t kc = (jc < C) ? cand[jc] : 0ull;
                uint64_t kd = (jd < C) ? cand[jd] : 0ull;
                #pragma unroll
                for (int q = 0; q < G; q++)
                    cnt[q] += (uint32_t)(ka > m[q]) + (uint32_t)(kb > m[q])
                            + (uint32_t)(kc > m[q]) + (uint32_t)(kd > m[q]);
            }
            #pragma unroll
            for (int q = 0; q < G; q++) cnt[q] = waveReduceSum(cnt[q]);
            if (lane == 0) {
                #pragma unroll
                for (int q = 0; q < G; q++) part[wave][q] = cnt[q];
            }
            __syncthreads();
            if (tid < G && b + tid < C) {
                uint32_t r = part[0][tid] + part[1][tid] + part[2][tid] + part[3][tid];
                if (r < K_PRE) {
                    int idx = (int)(~((uint32_t)cand[b + tid]));
                    float px1, py1, pw, ph;
                    compute_box(idx, deltas, px1, py1, pw, ph);
                    P[r] = make_float4(px1, py1, pw, ph);
                    float y2 = py1 + ph;
                    yk[r] = ((uint64_t)__float_as_uint(y2) << 32) | (uint32_t)(~r);
                }
            }
            __syncthreads();
        }
    }
    gridBarrier(2);

    // ---- phase 4: stable y2-desc rank + epilogue (OP, Q, Bnd) ----
    if (bid < K_PRE / G) {
        uint32_t (*part)[G] = (uint32_t (*)[G])smem;
        uint32_t b = (uint32_t)bid * G;
        uint64_t m[G];
        uint32_t cnt[G];
        #pragma unroll
        for (int q = 0; q < G; q++) {
            m[q] = yk[b + q];
            cnt[q] = 0u;
        }
        for (uint32_t j0 = 0; j0 < K_PRE; j0 += 1024) {
            uint32_t ja = j0 + tid, jb = ja + 256, jc = ja + 512, jd = ja + 768;
            uint64_t ka = (ja < K_PRE) ? yk[ja] : 0ull;
            uint64_t kb = (jb < K_PRE) ? yk[jb] : 0ull;
            uint64_t kc = (jc < K_PRE) ? yk[jc] : 0ull;
            uint64_t kd = (jd < K_PRE) ? yk[jd] : 0ull;
            #pragma unroll
            for (int q = 0; q < G; q++)
                cnt[q] += (uint32_t)(ka > m[q]) + (uint32_t)(kb > m[q])
                        + (uint32_t)(kc > m[q]) + (uint32_t)(kd > m[q]);
        }
        #pragma unroll
        for (int q = 0; q < G; q++) cnt[q] = waveReduceSum(cnt[q]);
        if (lane == 0) {
            #pragma unroll
            for (int q = 0; q < G; q++) part[wave][q] = cnt[q];
        }
        __syncthreads();
        if (tid < G) {
            uint32_t r = part[0][tid] + part[1][tid] + part[2][tid] + part[3][tid];
            float4 p = P[b + tid];
            OP[r] = p;
            float x1 = p.x, y1 = p.y;
            float x2 = x1 + p.z, y2 = y1 + p.w;
            float area = fmaxf((x2 - x1) * (y2 - y1), 1e-6f);
            Q[r] = make_float4(x1, y1, x2, y2);
            const double Mc = (double)0.7f - 0x1.0p-25;
            double c = Mc * (double)area;       // exact
            float Bf = (float)c;
            if (!((double)Bf > c)) Bf = __int_as_float(__float_as_int(Bf) + 1);
            Bnd[r] = Bf;
        }
    }
    gridBarrier(3);

    // ---- phase 5: suppression bitmask, tiled (grid-stride over 1128 tiles) ----
    {
        float4* qs = (float4*)smem;
        float*  bs = (float*)(smem + CT * 16);
        for (uint32_t t = bid; t < NTILE; t += NBLK) {
            int bx = (int)(t % ROWB);
            int by = (int)(t / ROWB);
            int i  = bx * 256 + tid;
            int c0 = by * CT;
            int ncols = min(CT, K_PRE - c0);
            bool rowok = (i < K_PRE);
            float4 qi = rowok ? Q[i] : make_float4(0.f, 0.f, 0.f, 0.f);
            __syncthreads();     // protect qs/bs from previous iteration's readers
            for (int j = tid; j < ncols; j += 256) {
                qs[j] = Q[c0 + j];
                bs[j] = Bnd[c0 + j];
            }
            __syncthreads();
            int nw = (ncols + 31) >> 5;
            for (int w = 0; w < nw; w++) {
                uint32_t bits = 0u;
                int jb = w * 32;
                int jn = min(32, ncols - jb);
                #pragma unroll 8
                for (int b = 0; b < jn; b++) {
                    int j = jb + b;
                    float4 qj = qs[j];
                    float iw = fminf(qi.z, qj.z) - fmaxf(qi.x, qj.x) + 1.0f;
                    iw = fmaxf(iw, 0.0f);
                    float ih = fminf(qi.w, qj.w) - fmaxf(qi.y, qj.y) + 1.0f;
                    ih = fmaxf(ih, 0.0f);
                    float d = iw * ih;
                    bits |= (d >= bs[j]) ? (1u << b) : 0u;
                }
                if (rowok) {
                    int gj = c0 + jb;
                    uint32_t selfo = (uint32_t)(i - gj);
                    if (selfo < 32u) bits &= ~(1u << selfo);     // j == i excluded
                    mask[(size_t)i * MW + (gj >> 5)] = bits;
                }
            }
        }
    }
    gridBarrier(4);
    if (bid != 0) return;

    // ---- phase 6: serial active scan, 256-row chunks (block 0 only) ----
    {
        uint32_t* rem  = (uint32_t*)smem;                // 192
        uint32_t* sidx = rem + 192;                      // 256
        uint32_t* svL  = sidx + CH;                      // 192
        uint32_t* pref = svL + 192;                      // 188
        uint32_t* nsSh = pref + MW;                      // 1
        // restore module-global invariant for the next replay
        if (tid < 16) {
            #pragma unroll
            for (int q = 0; q < 16; q++) g_hist[tid * 16 + q] = 0u;
        }
        if (tid == 16) g_cnt = 0u;
        if (tid < 192) { rem[tid] = 0u; svL[tid] = 0u; }
        for (int i = tid; i < K_POST * 4; i += 256) out[i] = 0.0f;
        __syncthreads();
        uint4 s00 = make_uint4(0,0,0,0), s01 = s00, s10 = s00, s11 = s00;
        uint4 s20 = s00, s21 = s00, s30 = s00, s31 = s00;
        if (tid < 64) {                      // chunk-0 row segments
            const uint32_t* p0 = mask + (size_t)(tid) * MW;
            s00 = *(const uint4*)p0;       s01 = *(const uint4*)(p0 + 4);
            const uint32_t* p1 = mask + (size_t)(64 + tid) * MW;
            s10 = *(const uint4*)p1;       s11 = *(const uint4*)(p1 + 4);
            const uint32_t* p2 = mask + (size_t)(128 + tid) * MW;
            s20 = *(const uint4*)p2;       s21 = *(const uint4*)(p2 + 4);
            const uint32_t* p3 = mask + (size_t)(192 + tid) * MW;
            s30 = *(const uint4*)p3;       s31 = *(const uint4*)(p3 + 4);
        }
        for (int c = 0; c < NCH; c++) {
            int base = c * CH;
            if (tid < 64) {
                uint64_t w0 = ~(((uint64_t)rem[8*c+1] << 32) | (uint64_t)rem[8*c+0]);
                uint64_t w1 = ~(((uint64_t)rem[8*c+3] << 32) | (uint64_t)rem[8*c+2]);
                uint64_t w2 = ~(((uint64_t)rem[8*c+5] << 32) | (uint64_t)rem[8*c+4]);
                uint64_t w3 = ~(((uint64_t)rem[8*c+7] << 32) | (uint64_t)rem[8*c+6]);
                int rows = K_PRE - base;                 // >=256 except last (112)
                if (rows < CH) {
                    auto msk = [](int v) -> uint64_t {
                        return v <= 0 ? 0ull : (v >= 64 ? ~0ull : ((1ull << v) - 1ull));
                    };
                    w0 &= msk(rows); w1 &= msk(rows - 64);
                    w2 &= msk(rows - 128); w3 &= msk(rows - 192);
                }
                uint64_t sv0 = 0ull, sv1 = 0ull, sv2 = 0ull, sv3 = 0ull;
                while (w0 | w1 | w2 | w3) {              // one iter per survivor
                    int k;
                    uint32_t a0, a1, a2, a3, a4, a5, a6, a7;
                    if (w0) {
                        k = __ffsll((unsigned long long)w0) - 1;
                        sv0 |= 1ull << k; w0 &= ~(1ull << k);
                        a0 = (uint32_t)__builtin_amdgcn_readlane((int)s00.x, k);
                        a1 = (uint32_t)__builtin_amdgcn_readlane((int)s00.y, k);
                        a2 = (uint32_t)__builtin_amdgcn_readlane((int)s00.z, k);
                        a3 = (uint32_t)__builtin_amdgcn_readlane((int)s00.w, k);
                        a4 = (uint32_t)__builtin_amdgcn_readlane((int)s01.x, k);
                        a5 = (uint32_t)__builtin_amdgcn_readlane((int)s01.y, k);
                        a6 = (uint32_t)__builtin_amdgcn_readlane((int)s01.z, k);
                        a7 = (uint32_t)__builtin_amdgcn_readlane((int)s01.w, k);
                    } else if (w1) {
                        k = __ffsll((unsigned long long)w1) - 1;
                        sv1 |= 1ull << k; w1 &= ~(1ull << k);
                        a0 = (uint32_t)__builtin_amdgcn_readlane((int)s10.x, k);
                        a1 = (uint32_t)__builtin_amdgcn_readlane((int)s10.y, k);
                        a2 = (uint32_t)__builtin_amdgcn_readlane((int)s10.z, k);
                        a3 = (uint32_t)__builtin_amdgcn_readlane((int)s10.w, k);
                        a4 = (uint32_t)__builtin_amdgcn_readlane((int)s11.x, k);
                        a5 = (uint32_t)__builtin_amdgcn_readlane((int)s11.y, k);
                        a6 = (uint32_t)__builtin_amdgcn_readlane((int)s11.z, k);
                        a7 = (uint32_t)__builtin_amdgcn_readlane((int)s11.w, k);
                    } else if (w2) {
                        k = __ffsll((unsigned long long)w2) - 1;
                        sv2 |= 1ull << k; w2 &= ~(1ull << k);
                        a0 = (uint32_t)__builtin_amdgcn_readlane((int)s20.x, k);
                        a1 = (uint32_t)__builtin_amdgcn_readlane((int)s20.y, k);
                        a2 = (uint32_t)__builtin_amdgcn_readlane((int)s20.z, k);
                        a3 = (uint32_t)__builtin_amdgcn_readlane((int)s20.w, k);
                        a4 = (uint32_t)__builtin_amdgcn_readlane((int)s21.x, k);
                        a5 = (uint32_t)__builtin_amdgcn_readlane((int)s21.y, k);
                        a6 = (uint32_t)__builtin_amdgcn_readlane((int)s21.z, k);
                        a7 = (uint32_t)__builtin_amdgcn_readlane((int)s21.w, k);
                    } else {
                        k = __ffsll((unsigned long long)w3) - 1;
                        sv3 |= 1ull << k; w3 &= ~(1ull << k);
                        a0 = (uint32_t)__builtin_amdgcn_readlane((int)s30.x, k);
                        a1 = (uint32_t)__builtin_amdgcn_readlane((int)s30.y, k);
                        a2 = (uint32_t)__builtin_amdgcn_readlane((int)s30.z, k);
                        a3 = (uint32_t)__builtin_amdgcn_readlane((int)s30.w, k);
                        a4 = (uint32_t)__builtin_amdgcn_readlane((int)s31.x, k);
                        a5 = (uint32_t)__builtin_amdgcn_readlane((int)s31.y, k);
                        a6 = (uint32_t)__builtin_amdgcn_readlane((int)s31.z, k);
                        a7 = (uint32_t)__builtin_amdgcn_readlane((int)s31.w, k);
                    }
                    w0 &= ~(((uint64_t)a1 << 32) | (uint64_t)a0);   // forward kills
                    w1 &= ~(((uint64_t)a3 << 32) | (uint64_t)a2);
                    w2 &= ~(((uint64_t)a5 << 32) | (uint64_t)a4);
                    w3 &= ~(((uint64_t)a7 << 32) | (uint64_t)a6);
                }
                uint32_t n0 = (uint32_t)__popcll(sv0), n1 = (uint32_t)__popcll(sv1);
                uint32_t n2 = (uint32_t)__popcll(sv2), n3 = (uint32_t)__popcll(sv3);
                uint32_t o1 = n0, o2 = n0 + n1, o3 = n0 + n1 + n2, ns = o3 + n3;
                if (tid == 0) {
                    svL[8*c+0] = (uint32_t)sv0; svL[8*c+1] = (uint32_t)(sv0 >> 32);
                    svL[8*c+2] = (uint32_t)sv1; svL[8*c+3] = (uint32_t)(sv1 >> 32);
                    svL[8*c+4] = (uint32_t)sv2; svL[8*c+5] = (uint32_t)(sv2 >> 32);
                    svL[8*c+6] = (uint32_t)sv3; svL[8*c+7] = (uint32_t)(sv3 >> 32);
                    nsSh[0] = ns;
                }
                uint64_t lowm = (1ull << tid) - 1ull;    // tid < 64
                if ((sv0 >> tid) & 1ull) sidx[      __popcll(sv0 & lowm)] = (uint32_t)(base + tid);
                if ((sv1 >> tid) & 1ull) sidx[o1 +  __popcll(sv1 & lowm)] = (uint32_t)(base + 64 + tid);
                if ((sv2 >> tid) & 1ull) sidx[o2 +  __popcll(sv2 & lowm)] = (uint32_t)(base + 128 + tid);
                if ((sv3 >> tid) & 1ull) sidx[o3 +  __popcll(sv3 & lowm)] = (uint32_t)(base + 192 + tid);
                if (ns) {               // pad to x32 with first survivor (OR-idempotent)
                    uint32_t nsPad = (ns + 31u) & ~31u;  // <= 256
                    uint32_t first;
                    if      (sv0) first = (uint32_t)base +       (uint32_t)(__ffsll((unsigned long long)sv0) - 1);
                    else if (sv1) first = (uint32_t)base + 64u + (uint32_t)(__ffsll((unsigned long long)sv1) - 1);
                    else if (sv2) first = (uint32_t)base + 128u+ (uint32_t)(__ffsll((unsigned long long)sv2) - 1);
                    else          first = (uint32_t)base + 192u+ (uint32_t)(__ffsll((unsigned long long)sv3) - 1);
                    #pragma unroll
                    for (int rr = 0; rr < 4; rr++) {
                        uint32_t ii = (uint32_t)tid + 64u * rr;
                        if (ii >= ns && ii < nsPad) sidx[ii] = first;
                    }
                }
                if (c + 1 < NCH) {      // prefetch next chunk rows (overlaps OR phase)
                    const uint32_t* p0 = mask + (size_t)(base + 256 + tid) * MW + 8*(c+1);
                    s00 = *(const uint4*)p0;  s01 = *(const uint4*)(p0 + 4);
                    const uint32_t* p1 = p0 + (size_t)64 * MW;
                    s10 = *(const uint4*)p1;  s11 = *(const uint4*)(p1 + 4);
                    const uint32_t* p2 = p1 + (size_t)64 * MW;
                    s20 = *(const uint4*)p2;  s21 = *(const uint4*)(p2 + 4);
                    const uint32_t* p3 = p2 + (size_t)64 * MW;
                    s30 = *(const uint4*)p3;  s31 = *(const uint4*)(p3 + 4);
                }
            }
            __syncthreads();
            int w = tid - 64;
            if (w >= 0 && w < MW) {
                uint32_t nsPad = (nsSh[0] + 31u) & ~31u;
                uint32_t acc = rem[w];
                for (uint32_t t2 = 0; t2 < nsPad; t2 += 32) {
                    uint32_t r[32];
                    #pragma unroll
                    for (int q = 0; q < 32; q++)
                        r[q] = mask[(size_t)sidx[t2 + q] * MW + w];
                    uint32_t o = 0u;
                    #pragma unroll
                    for (int q = 0; q < 32; q++) o |= r[q];
                    acc |= o;
                }
                rem[w] = acc;
            }
            __syncthreads();
        }
        // final validity + emit first 300 (tail already zeroed above)
        if (tid < MW) {
            uint32_t vv = svL[tid] & ~rem[tid];
            if (tid == MW - 1) vv &= 0xFFFFu;
            rem[tid] = vv;
        }
        __syncthreads();
        if (tid == 0) {
            uint32_t run = 0;
            for (int w2 = 0; w2 < MW; w2++) { pref[w2] = run; run += (uint32_t)__popc(rem[w2]); }
        }
        __syncthreads();
        if (tid < MW) {
            uint32_t b = rem[tid];
            uint32_t r = pref[tid];
            int basebit = tid * 32;
            while (b && r < K_POST) {
                int bit = __ffs(b) - 1;
                b &= b - 1u;
                float4 pp = OP[basebit + bit];
                *(float4*)(out + (size_t)r * 4) = pp;
                r++;
            }
        }
    }
}

extern "C" void kernel_launch(void* const* d_in, const int* in_sizes, int n_in,
                              void* d_out, int out_size, void* d_ws, size_t ws_size,
                              hipStream_t stream) {
    (void)in_sizes; (void)n_in; (void)out_size; (void)ws_size;
    const float* scores = (const float*)d_in[0];
    const float* deltas = (const float*)d_in[1];
    float* out = (float*)d_out;
    char* ws = (char*)d_ws;
    mega<<<NBLK, 256, 0, stream>>>(scores, deltas, out, ws);
}

// Round 7
// 237.694 us; speedup vs baseline: 1.7044x; 1.7044x over previous
//
#include <hip/hip_runtime.h>
#include <cstdint>
#include <cstddef>

#define N_TOT   147456      // 9*128*128
#define K_PRE   6000
#define K_POST  300
#define CAP     32768       // candidate cap (expected ~9.2K)
#define MW      188         // 6016 bits per mask row -> 188 u32 words
#define ROWS_PAD 6144       // 24*256 (scan prefetch range)
#define CH      256         // scan rows per chunk
#define NCH     24          // 24*256 = 6144
#define CT      128         // mask columns per tile
#define ROWB    24
#define COLB    47          // ceil(6000/128)
#define NTILE   (ROWB*COLB) // 1128 mask tiles
#define G       16          // candidates ranked per block
#define NBLK    576         // __launch_bounds__(256,4) => 1024 capacity, all resident
#define HBLK    144         // work blocks for hist/findbin (4 anchors/thread)

// workspace offsets (256-aligned); keys array eliminated (registers carry keys
// across phases 1->2). Total ~5 MiB.
#define OFF_CAND 0u
#define OFF_P    262144u
#define OFF_YK   358144u
#define OFF_OP   406272u
#define OFF_Q    502272u
#define OFF_BND  598272u
#define OFF_MASK 622336u    // + ROWS_PAD*MW*4 + 256 slack

__constant__ float c_sizes[9] = {4.f,8.f,12.f,16.f,24.f,32.f,48.f,64.f,96.f};

// Zero-initialized module globals. g_hist/g_cnt re-zeroed by phase 6 each run.
// g_bar is MONOTONIC (never reset): target = (ticket/NBLK+1)*NBLK, so graph
// replays compose without resets.
__device__ uint32_t g_hist[4096];
__device__ uint32_t g_cnt;
__device__ uint32_t g_bar[8];

// ---- line-granular coherence primitives (NO whole-L2 wbl2/inv ops) ----
// Relaxed agent-scope atomics set the sc1 scope bit: stores write through to
// the device coherence point; loads force-miss the local (incoherent) L2.
__device__ __forceinline__ uint32_t aload32(const uint32_t* p) {
    return __hip_atomic_load(p, __ATOMIC_RELAXED, __HIP_MEMORY_SCOPE_AGENT);
}
__device__ __forceinline__ uint64_t aload64(const uint64_t* p) {
    return __hip_atomic_load(p, __ATOMIC_RELAXED, __HIP_MEMORY_SCOPE_AGENT);
}
__device__ __forceinline__ void astore32(uint32_t* p, uint32_t v) {
    __hip_atomic_store(p, v, __ATOMIC_RELAXED, __HIP_MEMORY_SCOPE_AGENT);
}
__device__ __forceinline__ void astore64(uint64_t* p, uint64_t v) {
    __hip_atomic_store(p, v, __ATOMIC_RELAXED, __HIP_MEMORY_SCOPE_AGENT);
}
__device__ __forceinline__ void astoreF4(float4* p, float4 v) {
    union { float4 f; uint64_t u[2]; } c; c.f = v;
    astore64((uint64_t*)p, c.u[0]);
    astore64(((uint64_t*)p) + 1, c.u[1]);
}
__device__ __forceinline__ float4 aloadF4(const float4* p) {
    union { float4 f; uint64_t u[2]; } c;
    c.u[0] = aload64((const uint64_t*)p);
    c.u[1] = aload64(((const uint64_t*)p) + 1);
    return c.f;
}
__device__ __forceinline__ void aload8w(const uint32_t* p, uint4& lo, uint4& hi) {
    uint64_t a = aload64((const uint64_t*)p);
    uint64_t b = aload64((const uint64_t*)(p + 2));
    uint64_t c = aload64((const uint64_t*)(p + 4));
    uint64_t d = aload64((const uint64_t*)(p + 6));
    lo = make_uint4((uint32_t)a, (uint32_t)(a >> 32), (uint32_t)b, (uint32_t)(b >> 32));
    hi = make_uint4((uint32_t)c, (uint32_t)(c >> 32), (uint32_t)d, (uint32_t)(d >> 32));
}

// Flag barrier: __syncthreads() drains each thread's vmcnt (compiler emits
// s_waitcnt vmcnt(0) before s_barrier), so all this block's sc1 stores are at
// the coherence point before the arrival add. Readers' data loads are atomic
// (coherence-point) and issue only after the spin exits. No fences anywhere.
__device__ __forceinline__ void flagBarrier(int i) {
    __syncthreads();
    if (threadIdx.x == 0) {
        uint32_t ticket = __hip_atomic_fetch_add(&g_bar[i], 1u,
                              __ATOMIC_RELAXED, __HIP_MEMORY_SCOPE_AGENT);
        uint32_t target = (ticket / NBLK + 1u) * NBLK;
        uint32_t tries = 0;
        while (__hip_atomic_load(&g_bar[i], __ATOMIC_RELAXED,
                                 __HIP_MEMORY_SCOPE_AGENT) < target) {
            __builtin_amdgcn_s_sleep(8);
            if (++tries > (1u << 20)) break;             // fail loud, not hung
        }
        asm volatile("" ::: "memory");
    }
    __syncthreads();
}

// Bit-exact replication of reference box math (anchor + delta, clip).
__device__ __forceinline__ void compute_box(int idx, const float* __restrict__ deltas,
                                            float& px1, float& py1, float& pw, float& ph) {
    int a   = idx >> 14;
    int rem = idx & 16383;
    int h   = rem >> 7;
    int w   = rem & 127;
    float s    = c_sizes[a];
    float half = s * 0.5f;
    const float4 d = *(const float4*)(deltas + (size_t)a * 65536 + (size_t)rem * 4);
    float b0 = (((float)h + 0.5f) - half) + d.x;
    float b1 = (((float)w + 0.5f) - half) + d.y;
    float b2 = s + d.z;
    float b3 = s + d.w;
    b0 = fmaxf(b0, 0.0f); b1 = fmaxf(b1, 0.0f);
    b2 = fmaxf(b2, 0.0f); b3 = fmaxf(b3, 0.0f);
    float x1 = b0, y1 = b1;
    float x2 = b0 + b2, y2 = b1 + b3;
    x1 = fminf(x1, 128.0f); y1 = fminf(y1, 128.0f);
    x2 = fminf(x2, 128.0f); y2 = fminf(y2, 128.0f);
    px1 = x1; py1 = y1; pw = x2 - x1; ph = y2 - y1;
}

__device__ __forceinline__ uint32_t waveReduceSum(uint32_t v) {
    #pragma unroll
    for (int o = 32; o > 0; o >>= 1) v += __shfl_xor(v, o, 64);
    return v;
}

// ============================================================================
// Single fused kernel: 6 phases, 5 flag barriers, one dispatch. All
// cross-block/cross-phase data goes through agent-scope atomics only.
// ============================================================================
__global__ void __launch_bounds__(256, 4) mega(const float* __restrict__ scores,
                                               const float* __restrict__ deltas,
                                               float* __restrict__ out,
                                               char* __restrict__ ws) {
    __shared__ __align__(16) char smem[17664];

    uint64_t* cand = (uint64_t*)(ws + OFF_CAND);
    float4*   P    = (float4*)(ws + OFF_P);
    uint64_t* yk   = (uint64_t*)(ws + OFF_YK);
    float4*   OP   = (float4*)(ws + OFF_OP);
    float4*   Q    = (float4*)(ws + OFF_Q);
    float*    Bnd  = (float*)(ws + OFF_BND);
    uint32_t* mask = (uint32_t*)(ws + OFF_MASK);

    const int tid  = threadIdx.x;
    const int bid  = blockIdx.x;
    const int wave = tid >> 6, lane = tid & 63;

    uint32_t k4x = 0, k4y = 0, k4z = 0, k4w = 0;   // keys live in registers 1->2

    // ---- phase 1: keys + histogram (4 anchors/thread, blocks 0..143) ----
    if (bid < HBLK) {
        uint32_t* lh = (uint32_t*)smem;
        for (int i = tid; i < 4096; i += 256) lh[i] = 0u;
        __syncthreads();
        int t4 = (bid * 256 + tid) * 4;
        float4 sc4 = *(const float4*)(scores + t4);
        uint32_t k4[4];
        #pragma unroll
        for (int e = 0; e < 4; e++) {
            int idx = t4 + e;
            float px1, py1, pw, ph;
            compute_box(idx, deltas, px1, py1, pw, ph);
            bool keep = (pw >= 3.0f) && (ph >= 3.0f);
            float sc = (&sc4.x)[e];
            uint32_t key = keep ? __float_as_uint(sc) : 0u;
            k4[e] = key;
            atomicAdd(&lh[key >> 20], 1u);
        }
        k4x = k4[0]; k4y = k4[1]; k4z = k4[2]; k4w = k4[3];
        __syncthreads();
        for (int i = tid; i < 4096; i += 256) {
            uint32_t v = lh[i];
            if (v) atomicAdd(&g_hist[i], v);         // device-scope atomics
        }
    }
    flagBarrier(0);

    // ---- phase 2: findbin (suffix scan) + block-ticket compact ----
    if (bid < HBLK) {
        uint32_t* lh   = (uint32_t*)smem;
        uint32_t* seg  = (uint32_t*)(smem + 16384);
        uint32_t* bshp = (uint32_t*)(smem + 16384 + 1024);
        uint32_t* lcnt = bshp + 1;
        uint32_t* lbas = bshp + 2;
        if (tid == 0) lcnt[0] = 0u;
        for (int i = tid; i < 4096; i += 256) lh[i] = aload32(&g_hist[i]);
        __syncthreads();
        uint32_t s = 0;
        #pragma unroll
        for (int q = 0; q < 16; q++) s += lh[tid * 16 + q];
        seg[tid] = s;
        __syncthreads();
        for (int off = 1; off < 256; off <<= 1) {
            uint32_t v = seg[tid];
            if (tid + off < 256) v += seg[tid + off];
            __syncthreads();
            seg[tid] = v;
            __syncthreads();
        }
        uint32_t St  = seg[tid];
        uint32_t St1 = (tid < 255) ? seg[tid + 1] : 0u;
        if (St >= K_PRE && St1 < K_PRE) {
            uint32_t c2 = St1;
            uint32_t bstar = 0u;
            for (int q = 15; q >= 0; q--) {
                c2 += lh[tid * 16 + q];
                if (c2 >= K_PRE) { bstar = (uint32_t)(tid * 16 + q); break; }
            }
            bshp[0] = bstar;
        }
        if (tid == 0 && seg[0] < K_PRE) bshp[0] = 0u;
        __syncthreads();
        uint32_t bstar = bshp[0];
        int t4 = (bid * 256 + tid) * 4;
        bool s0 = (k4x >> 20) >= bstar;
        bool s1 = (k4y >> 20) >= bstar;
        bool s2 = (k4z >> 20) >= bstar;
        bool s3 = (k4w >> 20) >= bstar;
        uint32_t nsel = (uint32_t)s0 + s1 + s2 + s3;
        uint32_t myoff = 0u;
        if (nsel) myoff = atomicAdd(lcnt, nsel);
        __syncthreads();
        if (tid == 0) lbas[0] = atomicAdd(&g_cnt, lcnt[0]);
        __syncthreads();
        uint32_t pos = lbas[0] + myoff;
        if (s0) { if (pos < CAP) astore64(&cand[pos], ((uint64_t)k4x << 32) | (uint32_t)(~(uint32_t)(t4 + 0))); pos++; }
        if (s1) { if (pos < CAP) astore64(&cand[pos], ((uint64_t)k4y << 32) | (uint32_t)(~(uint32_t)(t4 + 1))); pos++; }
        if (s2) { if (pos < CAP) astore64(&cand[pos], ((uint64_t)k4z << 32) | (uint32_t)(~(uint32_t)(t4 + 2))); pos++; }
        if (s3) { if (pos < CAP) astore64(&cand[pos], ((uint64_t)k4w << 32) | (uint32_t)(~(uint32_t)(t4 + 3))); }
    }
    flagBarrier(1);

    // ---- phase 3: rank-by-count over candidates -> P, yk ----
    {
        uint32_t (*part)[G] = (uint32_t (*)[G])smem;
        uint32_t C = aload32(&g_cnt);
        if (C > CAP) C = CAP;
        uint32_t nGroups = (C + G - 1) / G;     // ~575 <= NBLK
        for (uint32_t g = bid; g < nGroups; g += NBLK) {
            uint32_t b = g * G;
            uint64_t m[G];
            uint32_t cnt[G];
            #pragma unroll
            for (int q = 0; q < G; q++) {
                m[q] = (b + q < C) ? aload64(&cand[b + q]) : ~0ull;
                cnt[q] = 0u;
            }
            for (uint32_t j0 = 0; j0 < C; j0 += 1024) {
                uint32_t ja = j0 + tid, jb = ja + 256, jc = ja + 512, jd = ja + 768;
                uint64_t ka = (ja < C) ? aload64(&cand[ja]) : 0ull;
                uint64_t kb = (jb < C) ? aload64(&cand[jb]) : 0ull;
                uint64_t kc = (jc < C) ? aload64(&cand[jc]) : 0ull;
                uint64_t kd = (jd < C) ? aload64(&cand[jd]) : 0ull;
                #pragma unroll
                for (int q = 0; q < G; q++)
                    cnt[q] += (uint32_t)(ka > m[q]) + (uint32_t)(kb > m[q])
                            + (uint32_t)(kc > m[q]) + (uint32_t)(kd > m[q]);
            }
            #pragma unroll
            for (int q = 0; q < G; q++) cnt[q] = waveReduceSum(cnt[q]);
            if (lane == 0) {
                #pragma unroll
                for (int q = 0; q < G; q++) part[wave][q] = cnt[q];
            }
            __syncthreads();
            if (tid < G && b + tid < C) {
                uint32_t r = part[0][tid] + part[1][tid] + part[2][tid] + part[3][tid];
                if (r < K_PRE) {
                    int idx = (int)(~((uint32_t)m[tid]));
                    float px1, py1, pw, ph;
                    compute_box(idx, deltas, px1, py1, pw, ph);
                    astoreF4(&P[r], make_float4(px1, py1, pw, ph));
                    float y2 = py1 + ph;
                    astore64(&yk[r], ((uint64_t)__float_as_uint(y2) << 32) | (uint32_t)(~r));
                }
            }
            __syncthreads();
        }
    }
    flagBarrier(2);

    // ---- phase 4: stable y2-desc rank + epilogue (OP, Q, Bnd) ----
    if (bid < K_PRE / G) {
        uint32_t (*part)[G] = (uint32_t (*)[G])smem;
        uint32_t b = (uint32_t)bid * G;
        uint64_t m[G];
        uint32_t cnt[G];
        #pragma unroll
        for (int q = 0; q < G; q++) {
            m[q] = aload64(&yk[b + q]);
            cnt[q] = 0u;
        }
        for (uint32_t j0 = 0; j0 < K_PRE; j0 += 1024) {
            uint32_t ja = j0 + tid, jb = ja + 256, jc = ja + 512, jd = ja + 768;
            uint64_t ka = (ja < K_PRE) ? aload64(&yk[ja]) : 0ull;
            uint64_t kb = (jb < K_PRE) ? aload64(&yk[jb]) : 0ull;
            uint64_t kc = (jc < K_PRE) ? aload64(&yk[jc]) : 0ull;
            uint64_t kd = (jd < K_PRE) ? aload64(&yk[jd]) : 0ull;
            #pragma unroll
            for (int q = 0; q < G; q++)
                cnt[q] += (uint32_t)(ka > m[q]) + (uint32_t)(kb > m[q])
                        + (uint32_t)(kc > m[q]) + (uint32_t)(kd > m[q]);
        }
        #pragma unroll
        for (int q = 0; q < G; q++) cnt[q] = waveReduceSum(cnt[q]);
        if (lane == 0) {
            #pragma unroll
            for (int q = 0; q < G; q++) part[wave][q] = cnt[q];
        }
        __syncthreads();
        if (tid < G) {
            uint32_t r = part[0][tid] + part[1][tid] + part[2][tid] + part[3][tid];
            float4 p = aloadF4(&P[b + tid]);
            astoreF4(&OP[r], p);
            float x1 = p.x, y1 = p.y;
            float x2 = x1 + p.z, y2 = y1 + p.w;
            float area = fmaxf((x2 - x1) * (y2 - y1), 1e-6f);
            astoreF4(&Q[r], make_float4(x1, y1, x2, y2));
            const double Mc = (double)0.7f - 0x1.0p-25;
            double c = Mc * (double)area;       // exact
            float Bf = (float)c;
            if (!((double)Bf > c)) Bf = __int_as_float(__float_as_int(Bf) + 1);
            astore32((uint32_t*)&Bnd[r], __float_as_uint(Bf));
        }
    }
    flagBarrier(3);

    // ---- phase 5: suppression bitmask, tiled (grid-stride over 1128 tiles) ----
    {
        float4* qs = (float4*)smem;
        float*  bs = (float*)(smem + CT * 16);
        for (uint32_t t = bid; t < NTILE; t += NBLK) {
            int bx = (int)(t % ROWB);
            int by = (int)(t / ROWB);
            int i  = bx * 256 + tid;
            int c0 = by * CT;
            int ncols = min(CT, K_PRE - c0);
            bool rowok = (i < K_PRE);
            float4 qi = rowok ? aloadF4(&Q[i]) : make_float4(0.f, 0.f, 0.f, 0.f);
            __syncthreads();     // protect qs/bs from previous iteration's readers
            for (int j = tid; j < ncols; j += 256) {
                qs[j] = aloadF4(&Q[c0 + j]);
                bs[j] = __uint_as_float(aload32((const uint32_t*)&Bnd[c0 + j]));
            }
            __syncthreads();
            int nw = (ncols + 31) >> 5;
            for (int w = 0; w < nw; w++) {
                uint32_t bits = 0u;
                int jb = w * 32;
                int jn = min(32, ncols - jb);
                #pragma unroll 8
                for (int b = 0; b < jn; b++) {
                    int j = jb + b;
                    float4 qj = qs[j];
                    float iw = fminf(qi.z, qj.z) - fmaxf(qi.x, qj.x) + 1.0f;
                    iw = fmaxf(iw, 0.0f);
                    float ih = fminf(qi.w, qj.w) - fmaxf(qi.y, qj.y) + 1.0f;
                    ih = fmaxf(ih, 0.0f);
                    float d = iw * ih;
                    bits |= (d >= bs[j]) ? (1u << b) : 0u;
                }
                if (rowok) {
                    int gj = c0 + jb;
                    uint32_t selfo = (uint32_t)(i - gj);
                    if (selfo < 32u) bits &= ~(1u << selfo);     // j == i excluded
                    astore32(&mask[(size_t)i * MW + (gj >> 5)], bits);
                }
            }
        }
    }
    flagBarrier(4);
    if (bid != 0) return;

    // ---- phase 6: serial active scan, 256-row chunks (block 0 only) ----
    {
        uint32_t* rem  = (uint32_t*)smem;                // 192
        uint32_t* sidx = rem + 192;                      // 256
        uint32_t* svL  = sidx + CH;                      // 192
        uint32_t* pref = svL + 192;                      // 188
        uint32_t* nsSh = pref + MW;                      // 1
        // restore module-global invariant for the next replay (plain stores:
        // flushed by kernel-end release before the next dispatch's atomics)
        if (tid < 16) {
            #pragma unroll
            for (int q = 0; q < 16; q++) g_hist[tid * 16 + q] = 0u;
        }
        if (tid == 16) g_cnt = 0u;
        if (tid < 192) { rem[tid] = 0u; svL[tid] = 0u; }
        for (int i = tid; i < K_POST * 4; i += 256) out[i] = 0.0f;
        __syncthreads();
        uint4 s00 = make_uint4(0,0,0,0), s01 = s00, s10 = s00, s11 = s00;
        uint4 s20 = s00, s21 = s00, s30 = s00, s31 = s00;
        if (tid < 64) {                      // chunk-0 row segments
            aload8w(mask + (size_t)(tid) * MW,       s00, s01);
            aload8w(mask + (size_t)(64 + tid) * MW,  s10, s11);
            aload8w(mask + (size_t)(128 + tid) * MW, s20, s21);
            aload8w(mask + (size_t)(192 + tid) * MW, s30, s31);
        }
        for (int c = 0; c < NCH; c++) {
            int base = c * CH;
            if (tid < 64) {
                uint64_t w0 = ~(((uint64_t)rem[8*c+1] << 32) | (uint64_t)rem[8*c+0]);
                uint64_t w1 = ~(((uint64_t)rem[8*c+3] << 32) | (uint64_t)rem[8*c+2]);
                uint64_t w2 = ~(((uint64_t)rem[8*c+5] << 32) | (uint64_t)rem[8*c+4]);
                uint64_t w3 = ~(((uint64_t)rem[8*c+7] << 32) | (uint64_t)rem[8*c+6]);
                int rows = K_PRE - base;                 // >=256 except last (112)
                if (rows < CH) {
                    auto msk = [](int v) -> uint64_t {
                        return v <= 0 ? 0ull : (v >= 64 ? ~0ull : ((1ull << v) - 1ull));
                    };
                    w0 &= msk(rows); w1 &= msk(rows - 64);
                    w2 &= msk(rows - 128); w3 &= msk(rows - 192);
                }
                uint64_t sv0 = 0ull, sv1 = 0ull, sv2 = 0ull, sv3 = 0ull;
                while (w0 | w1 | w2 | w3) {              // one iter per survivor
                    int k;
                    uint32_t a0, a1, a2, a3, a4, a5, a6, a7;
                    if (w0) {
                        k = __ffsll((unsigned long long)w0) - 1;
                        sv0 |= 1ull << k; w0 &= ~(1ull << k);
                        a0 = (uint32_t)__builtin_amdgcn_readlane((int)s00.x, k);
                        a1 = (uint32_t)__builtin_amdgcn_readlane((int)s00.y, k);
                        a2 = (uint32_t)__builtin_amdgcn_readlane((int)s00.z, k);
                        a3 = (uint32_t)__builtin_amdgcn_readlane((int)s00.w, k);
                        a4 = (uint32_t)__builtin_amdgcn_readlane((int)s01.x, k);
                        a5 = (uint32_t)__builtin_amdgcn_readlane((int)s01.y, k);
                        a6 = (uint32_t)__builtin_amdgcn_readlane((int)s01.z, k);
                        a7 = (uint32_t)__builtin_amdgcn_readlane((int)s01.w, k);
                    } else if (w1) {
                        k = __ffsll((unsigned long long)w1) - 1;
                        sv1 |= 1ull << k; w1 &= ~(1ull << k);
                        a0 = (uint32_t)__builtin_amdgcn_readlane((int)s10.x, k);
                        a1 = (uint32_t)__builtin_amdgcn_readlane((int)s10.y, k);
                        a2 = (uint32_t)__builtin_amdgcn_readlane((int)s10.z, k);
                        a3 = (uint32_t)__builtin_amdgcn_readlane((int)s10.w, k);
                        a4 = (uint32_t)__builtin_amdgcn_readlane((int)s11.x, k);
                        a5 = (uint32_t)__builtin_amdgcn_readlane((int)s11.y, k);
                        a6 = (uint32_t)__builtin_amdgcn_readlane((int)s11.z, k);
                        a7 = (uint32_t)__builtin_amdgcn_readlane((int)s11.w, k);
                    } else if (w2) {
                        k = __ffsll((unsigned long long)w2) - 1;
                        sv2 |= 1ull << k; w2 &= ~(1ull << k);
                        a0 = (uint32_t)__builtin_amdgcn_readlane((int)s20.x, k);
                        a1 = (uint32_t)__builtin_amdgcn_readlane((int)s20.y, k);
                        a2 = (uint32_t)__builtin_amdgcn_readlane((int)s20.z, k);
                        a3 = (uint32_t)__builtin_amdgcn_readlane((int)s20.w, k);
                        a4 = (uint32_t)__builtin_amdgcn_readlane((int)s21.x, k);
                        a5 = (uint32_t)__builtin_amdgcn_readlane((int)s21.y, k);
                        a6 = (uint32_t)__builtin_amdgcn_readlane((int)s21.z, k);
                        a7 = (uint32_t)__builtin_amdgcn_readlane((int)s21.w, k);
                    } else {
                        k = __ffsll((unsigned long long)w3) - 1;
                        sv3 |= 1ull << k; w3 &= ~(1ull << k);
                        a0 = (uint32_t)__builtin_amdgcn_readlane((int)s30.x, k);
                        a1 = (uint32_t)__builtin_amdgcn_readlane((int)s30.y, k);
                        a2 = (uint32_t)__builtin_amdgcn_readlane((int)s30.z, k);
                        a3 = (uint32_t)__builtin_amdgcn_readlane((int)s30.w, k);
                        a4 = (uint32_t)__builtin_amdgcn_readlane((int)s31.x, k);
                        a5 = (uint32_t)__builtin_amdgcn_readlane((int)s31.y, k);
                        a6 = (uint32_t)__builtin_amdgcn_readlane((int)s31.z, k);
                        a7 = (uint32_t)__builtin_amdgcn_readlane((int)s31.w, k);
                    }
                    w0 &= ~(((uint64_t)a1 << 32) | (uint64_t)a0);   // forward kills
                    w1 &= ~(((uint64_t)a3 << 32) | (uint64_t)a2);
                    w2 &= ~(((uint64_t)a5 << 32) | (uint64_t)a4);
                    w3 &= ~(((uint64_t)a7 << 32) | (uint64_t)a6);
                }
                uint32_t n0 = (uint32_t)__popcll(sv0), n1 = (uint32_t)__popcll(sv1);
                uint32_t n2 = (uint32_t)__popcll(sv2), n3 = (uint32_t)__popcll(sv3);
                uint32_t o1 = n0, o2 = n0 + n1, o3 = n0 + n1 + n2, ns = o3 + n3;
                if (tid == 0) {
                    svL[8*c+0] = (uint32_t)sv0; svL[8*c+1] = (uint32_t)(sv0 >> 32);
                    svL[8*c+2] = (uint32_t)sv1; svL[8*c+3] = (uint32_t)(sv1 >> 32);
                    svL[8*c+4] = (uint32_t)sv2; svL[8*c+5] = (uint32_t)(sv2 >> 32);
                    svL[8*c+6] = (uint32_t)sv3; svL[8*c+7] = (uint32_t)(sv3 >> 32);
                    nsSh[0] = ns;
                }
                uint64_t lowm = (1ull << tid) - 1ull;    // tid < 64
                if ((sv0 >> tid) & 1ull) sidx[      __popcll(sv0 & lowm)] = (uint32_t)(base + tid);
                if ((sv1 >> tid) & 1ull) sidx[o1 +  __popcll(sv1 & lowm)] = (uint32_t)(base + 64 + tid);
                if ((sv2 >> tid) & 1ull) sidx[o2 +  __popcll(sv2 & lowm)] = (uint32_t)(base + 128 + tid);
                if ((sv3 >> tid) & 1ull) sidx[o3 +  __popcll(sv3 & lowm)] = (uint32_t)(base + 192 + tid);
                if (ns) {               // pad to x32 with first survivor (OR-idempotent)
                    uint32_t nsPad = (ns + 31u) & ~31u;  // <= 256
                    uint32_t first;
                    if      (sv0) first = (uint32_t)base +       (uint32_t)(__ffsll((unsigned long long)sv0) - 1);
                    else if (sv1) first = (uint32_t)base + 64u + (uint32_t)(__ffsll((unsigned long long)sv1) - 1);
                    else if (sv2) first = (uint32_t)base + 128u+ (uint32_t)(__ffsll((unsigned long long)sv2) - 1);
                    else          first = (uint32_t)base + 192u+ (uint32_t)(__ffsll((unsigned long long)sv3) - 1);
                    #pragma unroll
                    for (int rr = 0; rr < 4; rr++) {
                        uint32_t ii = (uint32_t)tid + 64u * rr;
                        if (ii >= ns && ii < nsPad) sidx[ii] = first;
                    }
                }
                if (c + 1 < NCH) {      // prefetch next chunk rows (overlaps OR phase)
                    const uint32_t* p0 = mask + (size_t)(base + 256 + tid) * MW + 8*(c+1);
                    aload8w(p0, s00, s01);
                    aload8w(p0 + (size_t)64 * MW,  s10, s11);
                    aload8w(p0 + (size_t)128 * MW, s20, s21);
                    aload8w(p0 + (size_t)192 * MW, s30, s31);
                }
            }
            __syncthreads();
            int w = tid - 64;
            if (w >= 0 && w < MW) {
                uint32_t nsPad = (nsSh[0] + 31u) & ~31u;
                uint32_t acc = rem[w];
                for (uint32_t t2 = 0; t2 < nsPad; t2 += 32) {
                    uint32_t r[32];
                    #pragma unroll
                    for (int q = 0; q < 32; q++)
                        r[q] = aload32(&mask[(size_t)sidx[t2 + q] * MW + w]);
                    uint32_t o = 0u;
                    #pragma unroll
                    for (int q = 0; q < 32; q++) o |= r[q];
                    acc |= o;
                }
                rem[w] = acc;
            }
            __syncthreads();
        }
        // final validity + emit first 300 (tail already zeroed above)
        if (tid < MW) {
            uint32_t vv = svL[tid] & ~rem[tid];
            if (tid == MW - 1) vv &= 0xFFFFu;
            rem[tid] = vv;
        }
        __syncthreads();
        if (tid == 0) {
            uint32_t run = 0;
            for (int w2 = 0; w2 < MW; w2++) { pref[w2] = run; run += (uint32_t)__popc(rem[w2]); }
        }
        __syncthreads();
        if (tid < MW) {
            uint32_t b = rem[tid];
            uint32_t r = pref[tid];
            int basebit = tid * 32;
            while (b && r < K_POST) {
                int bit = __ffs(b) - 1;
                b &= b - 1u;
                float4 pp = aloadF4(&OP[basebit + bit]);
                *(float4*)(out + (size_t)r * 4) = pp;
                r++;
            }
        }
    }
}

extern "C" void kernel_launch(void* const* d_in, const int* in_sizes, int n_in,
                              void* d_out, int out_size, void* d_ws, size_t ws_size,
                              hipStream_t stream) {
    (void)in_sizes; (void)n_in; (void)out_size; (void)ws_size;
    const float* scores = (const float*)d_in[0];
    const float* deltas = (const float*)d_in[1];
    float* out = (float*)d_out;
    char* ws = (char*)d_ws;
    mega<<<NBLK, 256, 0, stream>>>(scores, deltas, out, ws);
}

// Round 8
// 174.933 us; speedup vs baseline: 2.3159x; 1.3588x over previous
//
#include <hip/hip_runtime.h>
#include <cstdint>
#include <cstddef>

#define N_TOT   147456      // 9*128*128
#define K_PRE   6000
#define K_POST  300
#define CAP     32768       // candidate cap (expected ~9.2K)
#define MW      188         // 6016 bits per mask row -> 188 u32 words
#define ROWS_PAD 6144       // 24*256 (scan prefetch range)
#define CH      256         // scan rows per chunk
#define NCH     24          // 24*256 = 6144
#define CT      128         // mask columns per tile
#define ROWB    24
#define COLB    47          // ceil(6000/128)
#define NTILE   (ROWB*COLB) // 1128 mask tiles
#define G       16          // candidates ranked per block
#define NBLK    576         // __launch_bounds__(256,4) => 1024 capacity, all resident
#define HBLK    144         // work blocks for hist/findbin (4 anchors/thread)
#define NGRP    24          // barrier tree: 24 groups x 24 blocks
#define GSZ     24

// workspace offsets (256-aligned); keys live in registers across phases 1->2.
#define OFF_CAND 0u
#define OFF_P    262144u
#define OFF_YK   358144u
#define OFF_OP   406272u
#define OFF_Q    502272u
#define OFF_BND  598272u
#define OFF_MASK 622336u    // + ROWS_PAD*MW*4 + 256 slack

__constant__ float c_sizes[9] = {4.f,8.f,12.f,16.f,24.f,32.f,48.f,64.f,96.f};

// Zero-initialized module globals. g_hist/g_cnt re-zeroed by phase 6 each run.
// Barrier counters are MONOTONIC (never reset): round = ticket/GSZ, root
// target = (round+1)*NGRP -> graph replays compose with no reset hazard.
__device__ uint32_t g_hist[4096];
__device__ uint32_t g_cnt;
__device__ uint32_t g_barL[8][NGRP * 16];   // leaf counters, 64B-padded
__device__ uint32_t g_barR[8 * 16];         // root counters, 64B-padded

// ---- line-granular coherence primitives (NO whole-L2 wbl2/inv ops) ----
__device__ __forceinline__ uint32_t aload32(const uint32_t* p) {
    return __hip_atomic_load(p, __ATOMIC_RELAXED, __HIP_MEMORY_SCOPE_AGENT);
}
__device__ __forceinline__ uint64_t aload64(const uint64_t* p) {
    return __hip_atomic_load(p, __ATOMIC_RELAXED, __HIP_MEMORY_SCOPE_AGENT);
}
__device__ __forceinline__ void astore32(uint32_t* p, uint32_t v) {
    __hip_atomic_store(p, v, __ATOMIC_RELAXED, __HIP_MEMORY_SCOPE_AGENT);
}
__device__ __forceinline__ void astore64(uint64_t* p, uint64_t v) {
    __hip_atomic_store(p, v, __ATOMIC_RELAXED, __HIP_MEMORY_SCOPE_AGENT);
}
__device__ __forceinline__ void astoreF4(float4* p, float4 v) {
    union { float4 f; uint64_t u[2]; } c; c.f = v;
    astore64((uint64_t*)p, c.u[0]);
    astore64(((uint64_t*)p) + 1, c.u[1]);
}
__device__ __forceinline__ float4 aloadF4(const float4* p) {
    union { float4 f; uint64_t u[2]; } c;
    c.u[0] = aload64((const uint64_t*)p);
    c.u[1] = aload64(((const uint64_t*)p) + 1);
    return c.f;
}
__device__ __forceinline__ void aload8w(const uint32_t* p, uint4& lo, uint4& hi) {
    uint64_t a = aload64((const uint64_t*)p);
    uint64_t b = aload64((const uint64_t*)(p + 2));
    uint64_t c = aload64((const uint64_t*)(p + 4));
    uint64_t d = aload64((const uint64_t*)(p + 6));
    lo = make_uint4((uint32_t)a, (uint32_t)(a >> 32), (uint32_t)b, (uint32_t)(b >> 32));
    hi = make_uint4((uint32_t)c, (uint32_t)(c >> 32), (uint32_t)d, (uint32_t)(d >> 32));
}

// 2-level tree barrier. Theory (rounds 1/6/7): same-address device-scope RMWs
// serialize at ~100-200cy each; a 576-way single-counter arrival = 25-48us.
// Tree: 24 parallel leaf chains of 24 + one root chain of 24 => ~3-5us.
// Waiters poll the root READ-ONLY with exponential s_sleep backoff.
// __syncthreads() before arrival drains vmcnt => this block's sc1 stores are
// at the coherence point before its ticket lands (round-7-verified model).
__device__ __forceinline__ void flagBarrier(int i) {
    __syncthreads();
    if (threadIdx.x == 0) {
        int grp = (int)(blockIdx.x / GSZ);          // 0..23
        uint32_t t = __hip_atomic_fetch_add(&g_barL[i][grp * 16], 1u,
                          __ATOMIC_RELAXED, __HIP_MEMORY_SCOPE_AGENT);
        uint32_t round = t / GSZ;
        if ((t % GSZ) == GSZ - 1u)                  // group complete -> root
            __hip_atomic_fetch_add(&g_barR[i * 16], 1u,
                __ATOMIC_RELAXED, __HIP_MEMORY_SCOPE_AGENT);
        uint32_t target = (round + 1u) * NGRP;
        uint32_t tries = 0;
        while (__hip_atomic_load(&g_barR[i * 16], __ATOMIC_RELAXED,
                                 __HIP_MEMORY_SCOPE_AGENT) < target) {
            if (tries < 8) __builtin_amdgcn_s_sleep(4);
            else           __builtin_amdgcn_s_sleep(64);
            if (++tries > (1u << 20)) break;        // fail loud, not hung
        }
        asm volatile("" ::: "memory");
    }
    __syncthreads();
}

// Bit-exact replication of reference box math (anchor + delta, clip).
__device__ __forceinline__ void compute_box(int idx, const float* __restrict__ deltas,
                                            float& px1, float& py1, float& pw, float& ph) {
    int a   = idx >> 14;
    int rem = idx & 16383;
    int h   = rem >> 7;
    int w   = rem & 127;
    float s    = c_sizes[a];
    float half = s * 0.5f;
    const float4 d = *(const float4*)(deltas + (size_t)a * 65536 + (size_t)rem * 4);
    float b0 = (((float)h + 0.5f) - half) + d.x;
    float b1 = (((float)w + 0.5f) - half) + d.y;
    float b2 = s + d.z;
    float b3 = s + d.w;
    b0 = fmaxf(b0, 0.0f); b1 = fmaxf(b1, 0.0f);
    b2 = fmaxf(b2, 0.0f); b3 = fmaxf(b3, 0.0f);
    float x1 = b0, y1 = b1;
    float x2 = b0 + b2, y2 = b1 + b3;
    x1 = fminf(x1, 128.0f); y1 = fminf(y1, 128.0f);
    x2 = fminf(x2, 128.0f); y2 = fminf(y2, 128.0f);
    px1 = x1; py1 = y1; pw = x2 - x1; ph = y2 - y1;
}

__device__ __forceinline__ uint32_t waveReduceSum(uint32_t v) {
    #pragma unroll
    for (int o = 32; o > 0; o >>= 1) v += __shfl_xor(v, o, 64);
    return v;
}

// ============================================================================
// Single fused kernel: 6 phases, 5 tree barriers, one dispatch. All
// cross-block/cross-phase data goes through agent-scope atomics only.
// ============================================================================
__global__ void __launch_bounds__(256, 4) mega(const float* __restrict__ scores,
                                               const float* __restrict__ deltas,
                                               float* __restrict__ out,
                                               char* __restrict__ ws) {
    __shared__ __align__(16) char smem[17664];

    uint64_t* cand = (uint64_t*)(ws + OFF_CAND);
    float4*   P    = (float4*)(ws + OFF_P);
    uint64_t* yk   = (uint64_t*)(ws + OFF_YK);
    float4*   OP   = (float4*)(ws + OFF_OP);
    float4*   Q    = (float4*)(ws + OFF_Q);
    float*    Bnd  = (float*)(ws + OFF_BND);
    uint32_t* mask = (uint32_t*)(ws + OFF_MASK);

    const int tid  = threadIdx.x;
    const int bid  = blockIdx.x;
    const int wave = tid >> 6, lane = tid & 63;

    uint32_t k4x = 0, k4y = 0, k4z = 0, k4w = 0;   // keys live in registers 1->2

    // ---- phase 1: keys + histogram (4 anchors/thread, blocks 0..143) ----
    if (bid < HBLK) {
        uint32_t* lh = (uint32_t*)smem;
        for (int i = tid; i < 4096; i += 256) lh[i] = 0u;
        __syncthreads();
        int t4 = (bid * 256 + tid) * 4;
        float4 sc4 = *(const float4*)(scores + t4);
        uint32_t k4[4];
        #pragma unroll
        for (int e = 0; e < 4; e++) {
            int idx = t4 + e;
            float px1, py1, pw, ph;
            compute_box(idx, deltas, px1, py1, pw, ph);
            bool keep = (pw >= 3.0f) && (ph >= 3.0f);
            float sc = (&sc4.x)[e];
            uint32_t key = keep ? __float_as_uint(sc) : 0u;
            k4[e] = key;
            atomicAdd(&lh[key >> 20], 1u);
        }
        k4x = k4[0]; k4y = k4[1]; k4z = k4[2]; k4w = k4[3];
        __syncthreads();
        for (int i = tid; i < 4096; i += 256) {
            uint32_t v = lh[i];
            if (v) atomicAdd(&g_hist[i], v);         // device-scope atomics
        }
    }
    flagBarrier(0);

    // ---- phase 2: findbin (suffix scan) + block-ticket compact ----
    if (bid < HBLK) {
        uint32_t* lh   = (uint32_t*)smem;
        uint32_t* seg  = (uint32_t*)(smem + 16384);
        uint32_t* bshp = (uint32_t*)(smem + 16384 + 1024);
        uint32_t* lcnt = bshp + 1;
        uint32_t* lbas = bshp + 2;
        if (tid == 0) lcnt[0] = 0u;
        for (int i = tid; i < 4096; i += 256) lh[i] = aload32(&g_hist[i]);
        __syncthreads();
        uint32_t s = 0;
        #pragma unroll
        for (int q = 0; q < 16; q++) s += lh[tid * 16 + q];
        seg[tid] = s;
        __syncthreads();
        for (int off = 1; off < 256; off <<= 1) {
            uint32_t v = seg[tid];
            if (tid + off < 256) v += seg[tid + off];
            __syncthreads();
            seg[tid] = v;
            __syncthreads();
        }
        uint32_t St  = seg[tid];
        uint32_t St1 = (tid < 255) ? seg[tid + 1] : 0u;
        if (St >= K_PRE && St1 < K_PRE) {
            uint32_t c2 = St1;
            uint32_t bstar = 0u;
            for (int q = 15; q >= 0; q--) {
                c2 += lh[tid * 16 + q];
                if (c2 >= K_PRE) { bstar = (uint32_t)(tid * 16 + q); break; }
            }
            bshp[0] = bstar;
        }
        if (tid == 0 && seg[0] < K_PRE) bshp[0] = 0u;
        __syncthreads();
        uint32_t bstar = bshp[0];
        int t4 = (bid * 256 + tid) * 4;
        bool s0 = (k4x >> 20) >= bstar;
        bool s1 = (k4y >> 20) >= bstar;
        bool s2 = (k4z >> 20) >= bstar;
        bool s3 = (k4w >> 20) >= bstar;
        uint32_t nsel = (uint32_t)s0 + s1 + s2 + s3;
        uint32_t myoff = 0u;
        if (nsel) myoff = atomicAdd(lcnt, nsel);
        __syncthreads();
        if (tid == 0) lbas[0] = atomicAdd(&g_cnt, lcnt[0]);
        __syncthreads();
        uint32_t pos = lbas[0] + myoff;
        if (s0) { if (pos < CAP) astore64(&cand[pos], ((uint64_t)k4x << 32) | (uint32_t)(~(uint32_t)(t4 + 0))); pos++; }
        if (s1) { if (pos < CAP) astore64(&cand[pos], ((uint64_t)k4y << 32) | (uint32_t)(~(uint32_t)(t4 + 1))); pos++; }
        if (s2) { if (pos < CAP) astore64(&cand[pos], ((uint64_t)k4z << 32) | (uint32_t)(~(uint32_t)(t4 + 2))); pos++; }
        if (s3) { if (pos < CAP) astore64(&cand[pos], ((uint64_t)k4w << 32) | (uint32_t)(~(uint32_t)(t4 + 3))); }
    }
    flagBarrier(1);

    // ---- phase 3: rank-by-count over candidates -> P, yk ----
    {
        uint32_t (*part)[G] = (uint32_t (*)[G])smem;
        uint32_t C = aload32(&g_cnt);
        if (C > CAP) C = CAP;
        uint32_t nGroups = (C + G - 1) / G;     // ~575 <= NBLK
        for (uint32_t g = bid; g < nGroups; g += NBLK) {
            uint32_t b = g * G;
            uint64_t m[G];
            uint32_t cnt[G];
            #pragma unroll
            for (int q = 0; q < G; q++) {
                m[q] = (b + q < C) ? aload64(&cand[b + q]) : ~0ull;
                cnt[q] = 0u;
            }
            for (uint32_t j0 = 0; j0 < C; j0 += 1024) {
                uint32_t ja = j0 + tid, jb = ja + 256, jc = ja + 512, jd = ja + 768;
                uint64_t ka = (ja < C) ? aload64(&cand[ja]) : 0ull;
                uint64_t kb = (jb < C) ? aload64(&cand[jb]) : 0ull;
                uint64_t kc = (jc < C) ? aload64(&cand[jc]) : 0ull;
                uint64_t kd = (jd < C) ? aload64(&cand[jd]) : 0ull;
                #pragma unroll
                for (int q = 0; q < G; q++)
                    cnt[q] += (uint32_t)(ka > m[q]) + (uint32_t)(kb > m[q])
                            + (uint32_t)(kc > m[q]) + (uint32_t)(kd > m[q]);
            }
            #pragma unroll
            for (int q = 0; q < G; q++) cnt[q] = waveReduceSum(cnt[q]);
            if (lane == 0) {
                #pragma unroll
                for (int q = 0; q < G; q++) part[wave][q] = cnt[q];
            }
            __syncthreads();
            if (tid < G && b + tid < C) {
                uint32_t r = part[0][tid] + part[1][tid] + part[2][tid] + part[3][tid];
                if (r < K_PRE) {
                    int idx = (int)(~((uint32_t)aload64(&cand[b + tid])));  // no runtime reg-array idx
                    float px1, py1, pw, ph;
                    compute_box(idx, deltas, px1, py1, pw, ph);
                    astoreF4(&P[r], make_float4(px1, py1, pw, ph));
                    float y2 = py1 + ph;
                    astore64(&yk[r], ((uint64_t)__float_as_uint(y2) << 32) | (uint32_t)(~r));
                }
            }
            __syncthreads();
        }
    }
    flagBarrier(2);

    // ---- phase 4: stable y2-desc rank + epilogue (OP, Q, Bnd) ----
    if (bid < K_PRE / G) {
        uint32_t (*part)[G] = (uint32_t (*)[G])smem;
        uint32_t b = (uint32_t)bid * G;
        uint64_t m[G];
        uint32_t cnt[G];
        #pragma unroll
        for (int q = 0; q < G; q++) {
            m[q] = aload64(&yk[b + q]);
            cnt[q] = 0u;
        }
        for (uint32_t j0 = 0; j0 < K_PRE; j0 += 1024) {
            uint32_t ja = j0 + tid, jb = ja + 256, jc = ja + 512, jd = ja + 768;
            uint64_t ka = (ja < K_PRE) ? aload64(&yk[ja]) : 0ull;
            uint64_t kb = (jb < K_PRE) ? aload64(&yk[jb]) : 0ull;
            uint64_t kc = (jc < K_PRE) ? aload64(&yk[jc]) : 0ull;
            uint64_t kd = (jd < K_PRE) ? aload64(&yk[jd]) : 0ull;
            #pragma unroll
            for (int q = 0; q < G; q++)
                cnt[q] += (uint32_t)(ka > m[q]) + (uint32_t)(kb > m[q])
                        + (uint32_t)(kc > m[q]) + (uint32_t)(kd > m[q]);
        }
        #pragma unroll
        for (int q = 0; q < G; q++) cnt[q] = waveReduceSum(cnt[q]);
        if (lane == 0) {
            #pragma unroll
            for (int q = 0; q < G; q++) part[wave][q] = cnt[q];
        }
        __syncthreads();
        if (tid < G) {
            uint32_t r = part[0][tid] + part[1][tid] + part[2][tid] + part[3][tid];
            float4 p = aloadF4(&P[b + tid]);
            astoreF4(&OP[r], p);
            float x1 = p.x, y1 = p.y;
            float x2 = x1 + p.z, y2 = y1 + p.w;
            float area = fmaxf((x2 - x1) * (y2 - y1), 1e-6f);
            astoreF4(&Q[r], make_float4(x1, y1, x2, y2));
            const double Mc = (double)0.7f - 0x1.0p-25;
            double c = Mc * (double)area;       // exact
            float Bf = (float)c;
            if (!((double)Bf > c)) Bf = __int_as_float(__float_as_int(Bf) + 1);
            astore32((uint32_t*)&Bnd[r], __float_as_uint(Bf));
        }
    }
    flagBarrier(3);

    // ---- phase 5: suppression bitmask, tiled (grid-stride over 1128 tiles) ----
    {
        float4* qs = (float4*)smem;
        float*  bs = (float*)(smem + CT * 16);
        for (uint32_t t = bid; t < NTILE; t += NBLK) {
            int bx = (int)(t % ROWB);
            int by = (int)(t / ROWB);
            int i  = bx * 256 + tid;
            int c0 = by * CT;
            int ncols = min(CT, K_PRE - c0);
            bool rowok = (i < K_PRE);
            float4 qi = rowok ? aloadF4(&Q[i]) : make_float4(0.f, 0.f, 0.f, 0.f);
            __syncthreads();     // protect qs/bs from previous iteration's readers
            for (int j = tid; j < ncols; j += 256) {
                qs[j] = aloadF4(&Q[c0 + j]);
                bs[j] = __uint_as_float(aload32((const uint32_t*)&Bnd[c0 + j]));
            }
            __syncthreads();
            int nw = (ncols + 31) >> 5;
            for (int w = 0; w < nw; w++) {
                uint32_t bits = 0u;
                int jb = w * 32;
                int jn = min(32, ncols - jb);
                #pragma unroll 8
                for (int b = 0; b < jn; b++) {
                    int j = jb + b;
                    float4 qj = qs[j];
                    float iw = fminf(qi.z, qj.z) - fmaxf(qi.x, qj.x) + 1.0f;
                    iw = fmaxf(iw, 0.0f);
                    float ih = fminf(qi.w, qj.w) - fmaxf(qi.y, qj.y) + 1.0f;
                    ih = fmaxf(ih, 0.0f);
                    float d = iw * ih;
                    bits |= (d >= bs[j]) ? (1u << b) : 0u;
                }
                if (rowok) {
                    int gj = c0 + jb;
                    uint32_t selfo = (uint32_t)(i - gj);
                    if (selfo < 32u) bits &= ~(1u << selfo);     // j == i excluded
                    astore32(&mask[(size_t)i * MW + (gj >> 5)], bits);
                }
            }
        }
    }
    flagBarrier(4);
    if (bid != 0) return;

    // ---- phase 6: serial active scan, 256-row chunks (block 0 only) ----
    {
        uint32_t* rem  = (uint32_t*)smem;                // 192
        uint32_t* sidx = rem + 192;                      // 256
        uint32_t* svL  = sidx + CH;                      // 192
        uint32_t* pref = svL + 192;                      // 188
        uint32_t* nsSh = pref + MW;                      // 1
        // restore module-global invariant for the next replay
        if (tid < 16) {
            #pragma unroll
            for (int q = 0; q < 16; q++) g_hist[tid * 16 + q] = 0u;
        }
        if (tid == 16) g_cnt = 0u;
        if (tid < 192) { rem[tid] = 0u; svL[tid] = 0u; }
        for (int i = tid; i < K_POST * 4; i += 256) out[i] = 0.0f;
        __syncthreads();
        uint4 s00 = make_uint4(0,0,0,0), s01 = s00, s10 = s00, s11 = s00;
        uint4 s20 = s00, s21 = s00, s30 = s00, s31 = s00;
        if (tid < 64) {                      // chunk-0 row segments
            aload8w(mask + (size_t)(tid) * MW,       s00, s01);
            aload8w(mask + (size_t)(64 + tid) * MW,  s10, s11);
            aload8w(mask + (size_t)(128 + tid) * MW, s20, s21);
            aload8w(mask + (size_t)(192 + tid) * MW, s30, s31);
        }
        for (int c = 0; c < NCH; c++) {
            int base = c * CH;
            if (tid < 64) {
                uint64_t w0 = ~(((uint64_t)rem[8*c+1] << 32) | (uint64_t)rem[8*c+0]);
                uint64_t w1 = ~(((uint64_t)rem[8*c+3] << 32) | (uint64_t)rem[8*c+2]);
                uint64_t w2 = ~(((uint64_t)rem[8*c+5] << 32) | (uint64_t)rem[8*c+4]);
                uint64_t w3 = ~(((uint64_t)rem[8*c+7] << 32) | (uint64_t)rem[8*c+6]);
                int rows = K_PRE - base;                 // >=256 except last (112)
                if (rows < CH) {
                    auto msk = [](int v) -> uint64_t {
                        return v <= 0 ? 0ull : (v >= 64 ? ~0ull : ((1ull << v) - 1ull));
                    };
                    w0 &= msk(rows); w1 &= msk(rows - 64);
                    w2 &= msk(rows - 128); w3 &= msk(rows - 192);
                }
                uint64_t sv0 = 0ull, sv1 = 0ull, sv2 = 0ull, sv3 = 0ull;
                while (w0 | w1 | w2 | w3) {              // one iter per survivor
                    int k;
                    uint32_t a0, a1, a2, a3, a4, a5, a6, a7;
                    if (w0) {
                        k = __ffsll((unsigned long long)w0) - 1;
                        sv0 |= 1ull << k; w0 &= ~(1ull << k);
                        a0 = (uint32_t)__builtin_amdgcn_readlane((int)s00.x, k);
                        a1 = (uint32_t)__builtin_amdgcn_readlane((int)s00.y, k);
                        a2 = (uint32_t)__builtin_amdgcn_readlane((int)s00.z, k);
                        a3 = (uint32_t)__builtin_amdgcn_readlane((int)s00.w, k);
                        a4 = (uint32_t)__builtin_amdgcn_readlane((int)s01.x, k);
                        a5 = (uint32_t)__builtin_amdgcn_readlane((int)s01.y, k);
                        a6 = (uint32_t)__builtin_amdgcn_readlane((int)s01.z, k);
                        a7 = (uint32_t)__builtin_amdgcn_readlane((int)s01.w, k);
                    } else if (w1) {
                        k = __ffsll((unsigned long long)w1) - 1;
                        sv1 |= 1ull << k; w1 &= ~(1ull << k);
                        a0 = (uint32_t)__builtin_amdgcn_readlane((int)s10.x, k);
                        a1 = (uint32_t)__builtin_amdgcn_readlane((int)s10.y, k);
                        a2 = (uint32_t)__builtin_amdgcn_readlane((int)s10.z, k);
                        a3 = (uint32_t)__builtin_amdgcn_readlane((int)s10.w, k);
                        a4 = (uint32_t)__builtin_amdgcn_readlane((int)s11.x, k);
                        a5 = (uint32_t)__builtin_amdgcn_readlane((int)s11.y, k);
                        a6 = (uint32_t)__builtin_amdgcn_readlane((int)s11.z, k);
                        a7 = (uint32_t)__builtin_amdgcn_readlane((int)s11.w, k);
                    } else if (w2) {
                        k = __ffsll((unsigned long long)w2) - 1;
                        sv2 |= 1ull << k; w2 &= ~(1ull << k);
                        a0 = (uint32_t)__builtin_amdgcn_readlane((int)s20.x, k);
                        a1 = (uint32_t)__builtin_amdgcn_readlane((int)s20.y, k);
                        a2 = (uint32_t)__builtin_amdgcn_readlane((int)s20.z, k);
                        a3 = (uint32_t)__builtin_amdgcn_readlane((int)s20.w, k);
                        a4 = (uint32_t)__builtin_amdgcn_readlane((int)s21.x, k);
                        a5 = (uint32_t)__builtin_amdgcn_readlane((int)s21.y, k);
                        a6 = (uint32_t)__builtin_amdgcn_readlane((int)s21.z, k);
                        a7 = (uint32_t)__builtin_amdgcn_readlane((int)s21.w, k);
                    } else {
                        k = __ffsll((unsigned long long)w3) - 1;
                        sv3 |= 1ull << k; w3 &= ~(1ull << k);
                        a0 = (uint32_t)__builtin_amdgcn_readlane((int)s30.x, k);
                        a1 = (uint32_t)__builtin_amdgcn_readlane((int)s30.y, k);
                        a2 = (uint32_t)__builtin_amdgcn_readlane((int)s30.z, k);
                        a3 = (uint32_t)__builtin_amdgcn_readlane((int)s30.w, k);
                        a4 = (uint32_t)__builtin_amdgcn_readlane((int)s31.x, k);
                        a5 = (uint32_t)__builtin_amdgcn_readlane((int)s31.y, k);
                        a6 = (uint32_t)__builtin_amdgcn_readlane((int)s31.z, k);
                        a7 = (uint32_t)__builtin_amdgcn_readlane((int)s31.w, k);
                    }
                    w0 &= ~(((uint64_t)a1 << 32) | (uint64_t)a0);   // forward kills
                    w1 &= ~(((uint64_t)a3 << 32) | (uint64_t)a2);
                    w2 &= ~(((uint64_t)a5 << 32) | (uint64_t)a4);
                    w3 &= ~(((uint64_t)a7 << 32) | (uint64_t)a6);
                }
                uint32_t n0 = (uint32_t)__popcll(sv0), n1 = (uint32_t)__popcll(sv1);
                uint32_t n2 = (uint32_t)__popcll(sv2), n3 = (uint32_t)__popcll(sv3);
                uint32_t o1 = n0, o2 = n0 + n1, o3 = n0 + n1 + n2, ns = o3 + n3;
                if (tid == 0) {
                    svL[8*c+0] = (uint32_t)sv0; svL[8*c+1] = (uint32_t)(sv0 >> 32);
                    svL[8*c+2] = (uint32_t)sv1; svL[8*c+3] = (uint32_t)(sv1 >> 32);
                    svL[8*c+4] = (uint32_t)sv2; svL[8*c+5] = (uint32_t)(sv2 >> 32);
                    svL[8*c+6] = (uint32_t)sv3; svL[8*c+7] = (uint32_t)(sv3 >> 32);
                    nsSh[0] = ns;
                }
                uint64_t lowm = (1ull << tid) - 1ull;    // tid < 64
                if ((sv0 >> tid) & 1ull) sidx[      __popcll(sv0 & lowm)] = (uint32_t)(base + tid);
                if ((sv1 >> tid) & 1ull) sidx[o1 +  __popcll(sv1 & lowm)] = (uint32_t)(base + 64 + tid);
                if ((sv2 >> tid) & 1ull) sidx[o2 +  __popcll(sv2 & lowm)] = (uint32_t)(base + 128 + tid);
                if ((sv3 >> tid) & 1ull) sidx[o3 +  __popcll(sv3 & lowm)] = (uint32_t)(base + 192 + tid);
                if (ns) {               // pad to x32 with first survivor (OR-idempotent)
                    uint32_t nsPad = (ns + 31u) & ~31u;  // <= 256
                    uint32_t first;
                    if      (sv0) first = (uint32_t)base +       (uint32_t)(__ffsll((unsigned long long)sv0) - 1);
                    else if (sv1) first = (uint32_t)base + 64u + (uint32_t)(__ffsll((unsigned long long)sv1) - 1);
                    else if (sv2) first = (uint32_t)base + 128u+ (uint32_t)(__ffsll((unsigned long long)sv2) - 1);
                    else          first = (uint32_t)base + 192u+ (uint32_t)(__ffsll((unsigned long long)sv3) - 1);
                    #pragma unroll
                    for (int rr = 0; rr < 4; rr++) {
                        uint32_t ii = (uint32_t)tid + 64u * rr;
                        if (ii >= ns && ii < nsPad) sidx[ii] = first;
                    }
                }
                if (c + 1 < NCH) {      // prefetch next chunk rows (overlaps OR phase)
                    const uint32_t* p0 = mask + (size_t)(base + 256 + tid) * MW + 8*(c+1);
                    aload8w(p0, s00, s01);
                    aload8w(p0 + (size_t)64 * MW,  s10, s11);
                    aload8w(p0 + (size_t)128 * MW, s20, s21);
                    aload8w(p0 + (size_t)192 * MW, s30, s31);
                }
            }
            __syncthreads();
            int w = tid - 64;
            if (w >= 0 && w < MW) {
                uint32_t nsPad = (nsSh[0] + 31u) & ~31u;
                uint32_t acc = rem[w];
                for (uint32_t t2 = 0; t2 < nsPad; t2 += 32) {
                    uint32_t r[32];
                    #pragma unroll
                    for (int q = 0; q < 32; q++)
                        r[q] = aload32(&mask[(size_t)sidx[t2 + q] * MW + w]);
                    uint32_t o = 0u;
                    #pragma unroll
                    for (int q = 0; q < 32; q++) o |= r[q];
                    acc |= o;
                }
                rem[w] = acc;
            }
            __syncthreads();
        }
        // final validity + emit first 300 (tail already zeroed above)
        if (tid < MW) {
            uint32_t vv = svL[tid] & ~rem[tid];
            if (tid == MW - 1) vv &= 0xFFFFu;
            rem[tid] = vv;
        }
        __syncthreads();
        if (tid == 0) {
            uint32_t run = 0;
            for (int w2 = 0; w2 < MW; w2++) { pref[w2] = run; run += (uint32_t)__popc(rem[w2]); }
        }
        __syncthreads();
        if (tid < MW) {
            uint32_t b = rem[tid];
            uint32_t r = pref[tid];
            int basebit = tid * 32;
            while (b && r < K_POST) {
                int bit = __ffs(b) - 1;
                b &= b - 1u;
                float4 pp = aloadF4(&OP[basebit + bit]);
                *(float4*)(out + (size_t)r * 4) = pp;
                r++;
            }
        }
    }
}

extern "C" void kernel_launch(void* const* d_in, const int* in_sizes, int n_in,
                              void* d_out, int out_size, void* d_ws, size_t ws_size,
                              hipStream_t stream) {
    (void)in_sizes; (void)n_in; (void)out_size; (void)ws_size;
    const float* scores = (const float*)d_in[0];
    const float* deltas = (const float*)d_in[1];
    float* out = (float*)d_out;
    char* ws = (char*)d_ws;
    mega<<<NBLK, 256, 0, stream>>>(scores, deltas, out, ws);
}

// Round 9
// 159.352 us; speedup vs baseline: 2.5423x; 1.0978x over previous
//
#include <hip/hip_runtime.h>
#include <cstdint>
#include <cstddef>

#define N_TOT   147456      // 9*128*128
#define K_PRE   6000
#define K_POST  300
#define CAP     32768       // candidate cap (expected ~9.2K)
#define MW      188         // 6016 bits per mask row -> 188 u32 words
#define ROWS_PAD 6144       // 24*256 (scan prefetch range)
#define CH      256         // scan rows per chunk
#define NCH     24          // 24*256 = 6144
#define CT      128         // mask columns per tile
#define ROWB    24
#define COLB    47          // ceil(6000/128)
#define NTILE   (ROWB*COLB) // 1128 mask tiles
#define G       16          // candidates ranked per block
#define NBLK    576         // __launch_bounds__(256,4) => 1024 capacity, all resident
#define HBLK    144         // work blocks for hist/findbin (4 anchors/thread)
#define NGRP    24          // barrier tree: 24 groups x 24 blocks
#define GSZ     24

// workspace offsets (256-aligned); keys live in registers across phases 1->2.
#define OFF_CAND 0u
#define OFF_P    262144u
#define OFF_YK   358144u
#define OFF_OP   406272u
#define OFF_Q    502272u
#define OFF_BND  598272u
#define OFF_MASK 622336u    // + ROWS_PAD*MW*4 + 256 slack

__constant__ float c_sizes[9] = {4.f,8.f,12.f,16.f,24.f,32.f,48.f,64.f,96.f};

// Zero-initialized module globals. g_hist/g_cnt re-zeroed by phase 6 each run
// (plain stores by block 0; kernel-end release writes them back).
// Barrier counters/releases are MONOTONIC (never reset) -> replay-safe.
__device__ uint32_t g_hist[4096];
__device__ uint32_t g_cnt;
__device__ uint32_t g_barL[8][NGRP * 16];   // leaf arrival counters, 64B-padded
__device__ uint32_t g_barR[8 * 16];         // root counters, 64B-padded
__device__ uint32_t g_rel[8][NGRP * 16];    // per-group release flags, 64B-padded

// ---- coherence model (validated r7/r8: absmax=0, FETCH drop) ----
// WRITES to cross-phase data use sc1 (agent-scope relaxed atomic store):
// write-through to the device coherence point, no whole-L2 maintenance.
// READS after the barrier are PLAIN: L2s are invalidated at kernel launch
// (the split pipeline's correctness proves this), and no region is
// plain-touched before its sc1 writes -> no XCD can hold a stale line.
__device__ __forceinline__ void astore32(uint32_t* p, uint32_t v) {
    __hip_atomic_store(p, v, __ATOMIC_RELAXED, __HIP_MEMORY_SCOPE_AGENT);
}
__device__ __forceinline__ void astore64(uint64_t* p, uint64_t v) {
    __hip_atomic_store(p, v, __ATOMIC_RELAXED, __HIP_MEMORY_SCOPE_AGENT);
}
__device__ __forceinline__ void astoreF4(float4* p, float4 v) {
    union { float4 f; uint64_t u[2]; } c; c.f = v;
    astore64((uint64_t*)p, c.u[0]);
    astore64(((uint64_t*)p) + 1, c.u[1]);
}

// 2-level arrival tree + broadcast release. Arrival: 24 parallel leaf chains
// of 24 RMWs + one root chain of 24 (r8: -68us vs flat 576-chain). Release:
// only group leaders poll the root; members poll their group's release line
// (<=24 pollers per address -> no same-line poll storm).
__device__ __forceinline__ void flagBarrier(int i) {
    __syncthreads();   // drains vmcnt: this block's sc1 stores are at the
                       // coherence point before its ticket lands (r7 model)
    if (threadIdx.x == 0) {
        int grp = (int)(blockIdx.x / GSZ);          // 0..23
        int mem = (int)(blockIdx.x % GSZ);
        uint32_t t = __hip_atomic_fetch_add(&g_barL[i][grp * 16], 1u,
                          __ATOMIC_RELAXED, __HIP_MEMORY_SCOPE_AGENT);
        uint32_t round = t / GSZ;
        if ((t % GSZ) == GSZ - 1u)                  // group complete -> root
            __hip_atomic_fetch_add(&g_barR[i * 16], 1u,
                __ATOMIC_RELAXED, __HIP_MEMORY_SCOPE_AGENT);
        uint32_t tries = 0;
        if (mem == 0) {                             // leader: poll root, release group
            uint32_t target = (round + 1u) * NGRP;
            while (__hip_atomic_load(&g_barR[i * 16], __ATOMIC_RELAXED,
                                     __HIP_MEMORY_SCOPE_AGENT) < target) {
                __builtin_amdgcn_s_sleep(4);
                if (++tries > (1u << 20)) break;    // fail loud, not hung
            }
            astore32(&g_rel[i][grp * 16], round + 1u);
        } else {                                    // member: poll group release
            while (__hip_atomic_load(&g_rel[i][grp * 16], __ATOMIC_RELAXED,
                                     __HIP_MEMORY_SCOPE_AGENT) < round + 1u) {
                __builtin_amdgcn_s_sleep(4);
                if (++tries > (1u << 20)) break;
            }
        }
        asm volatile("" ::: "memory");
    }
    __syncthreads();
}

// Bit-exact replication of reference box math (anchor + delta, clip).
__device__ __forceinline__ void compute_box(int idx, const float* __restrict__ deltas,
                                            float& px1, float& py1, float& pw, float& ph) {
    int a   = idx >> 14;
    int rem = idx & 16383;
    int h   = rem >> 7;
    int w   = rem & 127;
    float s    = c_sizes[a];
    float half = s * 0.5f;
    const float4 d = *(const float4*)(deltas + (size_t)a * 65536 + (size_t)rem * 4);
    float b0 = (((float)h + 0.5f) - half) + d.x;
    float b1 = (((float)w + 0.5f) - half) + d.y;
    float b2 = s + d.z;
    float b3 = s + d.w;
    b0 = fmaxf(b0, 0.0f); b1 = fmaxf(b1, 0.0f);
    b2 = fmaxf(b2, 0.0f); b3 = fmaxf(b3, 0.0f);
    float x1 = b0, y1 = b1;
    float x2 = b0 + b2, y2 = b1 + b3;
    x1 = fminf(x1, 128.0f); y1 = fminf(y1, 128.0f);
    x2 = fminf(x2, 128.0f); y2 = fminf(y2, 128.0f);
    px1 = x1; py1 = y1; pw = x2 - x1; ph = y2 - y1;
}

__device__ __forceinline__ uint32_t waveReduceSum(uint32_t v) {
    #pragma unroll
    for (int o = 32; o > 0; o >>= 1) v += __shfl_xor(v, o, 64);
    return v;
}

// ============================================================================
// Single fused kernel: 6 phases, 5 tree barriers, one dispatch.
// sc1 writes + plain post-barrier reads + 16B-vectorized mask stores.
// ============================================================================
__global__ void __launch_bounds__(256, 4) mega(const float* __restrict__ scores,
                                               const float* __restrict__ deltas,
                                               float* __restrict__ out,
                                               char* __restrict__ ws) {
    __shared__ __align__(16) char smem[17664];

    uint64_t* cand = (uint64_t*)(ws + OFF_CAND);
    float4*   P    = (float4*)(ws + OFF_P);
    uint64_t* yk   = (uint64_t*)(ws + OFF_YK);
    float4*   OP   = (float4*)(ws + OFF_OP);
    float4*   Q    = (float4*)(ws + OFF_Q);
    float*    Bnd  = (float*)(ws + OFF_BND);
    uint32_t* mask = (uint32_t*)(ws + OFF_MASK);

    const int tid  = threadIdx.x;
    const int bid  = blockIdx.x;
    const int wave = tid >> 6, lane = tid & 63;

    uint32_t k4x = 0, k4y = 0, k4z = 0, k4w = 0;   // keys live in registers 1->2

    // ---- phase 1: keys + histogram (4 anchors/thread, blocks 0..143) ----
    if (bid < HBLK) {
        uint32_t* lh = (uint32_t*)smem;
        for (int i = tid; i < 4096; i += 256) lh[i] = 0u;
        __syncthreads();
        int t4 = (bid * 256 + tid) * 4;
        float4 sc4 = *(const float4*)(scores + t4);
        uint32_t k4[4];
        #pragma unroll
        for (int e = 0; e < 4; e++) {
            int idx = t4 + e;
            float px1, py1, pw, ph;
            compute_box(idx, deltas, px1, py1, pw, ph);
            bool keep = (pw >= 3.0f) && (ph >= 3.0f);
            float sc = (&sc4.x)[e];
            uint32_t key = keep ? __float_as_uint(sc) : 0u;
            k4[e] = key;
            atomicAdd(&lh[key >> 20], 1u);
        }
        k4x = k4[0]; k4y = k4[1]; k4z = k4[2]; k4w = k4[3];
        __syncthreads();
        for (int i = tid; i < 4096; i += 256) {
            uint32_t v = lh[i];
            if (v) atomicAdd(&g_hist[i], v);         // device-scope RMW @ coherence point
        }
    }
    flagBarrier(0);

    // ---- phase 2: findbin (suffix scan) + block-ticket compact ----
    if (bid < HBLK) {
        uint32_t* lh   = (uint32_t*)smem;
        uint32_t* seg  = (uint32_t*)(smem + 16384);
        uint32_t* bshp = (uint32_t*)(smem + 16384 + 1024);
        uint32_t* lcnt = bshp + 1;
        uint32_t* lbas = bshp + 2;
        if (tid == 0) lcnt[0] = 0u;
        for (int i = tid; i < 4096; i += 256) lh[i] = g_hist[i];   // plain: L2 miss -> L3, correct
        __syncthreads();
        uint32_t s = 0;
        #pragma unroll
        for (int q = 0; q < 16; q++) s += lh[tid * 16 + q];
        seg[tid] = s;
        __syncthreads();
        for (int off = 1; off < 256; off <<= 1) {
            uint32_t v = seg[tid];
            if (tid + off < 256) v += seg[tid + off];
            __syncthreads();
            seg[tid] = v;
            __syncthreads();
        }
        uint32_t St  = seg[tid];
        uint32_t St1 = (tid < 255) ? seg[tid + 1] : 0u;
        if (St >= K_PRE && St1 < K_PRE) {
            uint32_t c2 = St1;
            uint32_t bstar = 0u;
            for (int q = 15; q >= 0; q--) {
                c2 += lh[tid * 16 + q];
                if (c2 >= K_PRE) { bstar = (uint32_t)(tid * 16 + q); break; }
            }
            bshp[0] = bstar;
        }
        if (tid == 0 && seg[0] < K_PRE) bshp[0] = 0u;
        __syncthreads();
        uint32_t bstar = bshp[0];
        int t4 = (bid * 256 + tid) * 4;
        bool s0 = (k4x >> 20) >= bstar;
        bool s1 = (k4y >> 20) >= bstar;
        bool s2 = (k4z >> 20) >= bstar;
        bool s3 = (k4w >> 20) >= bstar;
        uint32_t nsel = (uint32_t)s0 + s1 + s2 + s3;
        uint32_t myoff = 0u;
        if (nsel) myoff = atomicAdd(lcnt, nsel);
        __syncthreads();
        if (tid == 0) lbas[0] = atomicAdd(&g_cnt, lcnt[0]);
        __syncthreads();
        uint32_t pos = lbas[0] + myoff;
        if (s0) { if (pos < CAP) astore64(&cand[pos], ((uint64_t)k4x << 32) | (uint32_t)(~(uint32_t)(t4 + 0))); pos++; }
        if (s1) { if (pos < CAP) astore64(&cand[pos], ((uint64_t)k4y << 32) | (uint32_t)(~(uint32_t)(t4 + 1))); pos++; }
        if (s2) { if (pos < CAP) astore64(&cand[pos], ((uint64_t)k4z << 32) | (uint32_t)(~(uint32_t)(t4 + 2))); pos++; }
        if (s3) { if (pos < CAP) astore64(&cand[pos], ((uint64_t)k4w << 32) | (uint32_t)(~(uint32_t)(t4 + 3))); }
    }
    flagBarrier(1);

    // ---- phase 3: rank-by-count over candidates -> P, yk (plain cand reads) ----
    {
        uint32_t (*part)[G] = (uint32_t (*)[G])smem;
        uint32_t C = g_cnt;                     // plain: L2 miss -> coherence point
        if (C > CAP) C = CAP;
        uint32_t nGroups = (C + G - 1) / G;     // ~575 <= NBLK
        for (uint32_t g = bid; g < nGroups; g += NBLK) {
            uint32_t b = g * G;
            uint64_t m[G];
            uint32_t cnt[G];
            #pragma unroll
            for (int q = 0; q < G; q++) {
                m[q] = (b + q < C) ? cand[b + q] : ~0ull;
                cnt[q] = 0u;
            }
            for (uint32_t j0 = 0; j0 < C; j0 += 1024) {
                uint32_t ja = j0 + tid, jb = ja + 256, jc = ja + 512, jd = ja + 768;
                uint64_t ka = (ja < C) ? cand[ja] : 0ull;   // plain: L2-cached re-reads
                uint64_t kb = (jb < C) ? cand[jb] : 0ull;
                uint64_t kc = (jc < C) ? cand[jc] : 0ull;
                uint64_t kd = (jd < C) ? cand[jd] : 0ull;
                #pragma unroll
                for (int q = 0; q < G; q++)
                    cnt[q] += (uint32_t)(ka > m[q]) + (uint32_t)(kb > m[q])
                            + (uint32_t)(kc > m[q]) + (uint32_t)(kd > m[q]);
            }
            #pragma unroll
            for (int q = 0; q < G; q++) cnt[q] = waveReduceSum(cnt[q]);
            if (lane == 0) {
                #pragma unroll
                for (int q = 0; q < G; q++) part[wave][q] = cnt[q];
            }
            __syncthreads();
            if (tid < G && b + tid < C) {
                uint32_t r = part[0][tid] + part[1][tid] + part[2][tid] + part[3][tid];
                if (r < K_PRE) {
                    int idx = (int)(~((uint32_t)cand[b + tid]));
                    float px1, py1, pw, ph;
                    compute_box(idx, deltas, px1, py1, pw, ph);
                    astoreF4(&P[r], make_float4(px1, py1, pw, ph));
                    float y2 = py1 + ph;
                    astore64(&yk[r], ((uint64_t)__float_as_uint(y2) << 32) | (uint32_t)(~r));
                }
            }
            __syncthreads();
        }
    }
    flagBarrier(2);

    // ---- phase 4: stable y2-desc rank + epilogue (plain yk/P reads) ----
    if (bid < K_PRE / G) {
        uint32_t (*part)[G] = (uint32_t (*)[G])smem;
        uint32_t b = (uint32_t)bid * G;
        uint64_t m[G];
        uint32_t cnt[G];
        #pragma unroll
        for (int q = 0; q < G; q++) {
            m[q] = yk[b + q];
            cnt[q] = 0u;
        }
        for (uint32_t j0 = 0; j0 < K_PRE; j0 += 1024) {
            uint32_t ja = j0 + tid, jb = ja + 256, jc = ja + 512, jd = ja + 768;
            uint64_t ka = (ja < K_PRE) ? yk[ja] : 0ull;
            uint64_t kb = (jb < K_PRE) ? yk[jb] : 0ull;
            uint64_t kc = (jc < K_PRE) ? yk[jc] : 0ull;
            uint64_t kd = (jd < K_PRE) ? yk[jd] : 0ull;
            #pragma unroll
            for (int q = 0; q < G; q++)
                cnt[q] += (uint32_t)(ka > m[q]) + (uint32_t)(kb > m[q])
                        + (uint32_t)(kc > m[q]) + (uint32_t)(kd > m[q]);
        }
        #pragma unroll
        for (int q = 0; q < G; q++) cnt[q] = waveReduceSum(cnt[q]);
        if (lane == 0) {
            #pragma unroll
            for (int q = 0; q < G; q++) part[wave][q] = cnt[q];
        }
        __syncthreads();
        if (tid < G) {
            uint32_t r = part[0][tid] + part[1][tid] + part[2][tid] + part[3][tid];
            float4 p = P[b + tid];
            astoreF4(&OP[r], p);
            float x1 = p.x, y1 = p.y;
            float x2 = x1 + p.z, y2 = y1 + p.w;
            float area = fmaxf((x2 - x1) * (y2 - y1), 1e-6f);
            astoreF4(&Q[r], make_float4(x1, y1, x2, y2));
            const double Mc = (double)0.7f - 0x1.0p-25;
            double c = Mc * (double)area;       // exact
            float Bf = (float)c;
            if (!((double)Bf > c)) Bf = __int_as_float(__float_as_int(Bf) + 1);
            astore32((uint32_t*)&Bnd[r], __float_as_uint(Bf));
        }
    }
    flagBarrier(3);

    // ---- phase 5: suppression bitmask (plain Q/Bnd reads, 16B mask writes) ----
    {
        float4* qs = (float4*)smem;
        float*  bs = (float*)(smem + CT * 16);
        for (uint32_t t = bid; t < NTILE; t += NBLK) {
            int bx = (int)(t % ROWB);
            int by = (int)(t / ROWB);
            int i  = bx * 256 + tid;
            int c0 = by * CT;
            int ncols = min(CT, K_PRE - c0);        // 128 or 112 (last col tile)
            bool rowok = (i < K_PRE);
            float4 qi = rowok ? Q[i] : make_float4(0.f, 0.f, 0.f, 0.f);
            __syncthreads();     // protect qs/bs from previous iteration's readers
            for (int j = tid; j < ncols; j += 256) {
                qs[j] = Q[c0 + j];
                bs[j] = Bnd[c0 + j];
            }
            __syncthreads();
            uint32_t bw[4];
            #pragma unroll
            for (int w = 0; w < 4; w++) {
                uint32_t bits = 0u;
                int jb = w * 32;
                int jn = min(32, ncols - jb);       // >=16 always
                #pragma unroll 8
                for (int b = 0; b < jn; b++) {
                    int j = jb + b;
                    float4 qj = qs[j];
                    float iw = fminf(qi.z, qj.z) - fmaxf(qi.x, qj.x) + 1.0f;
                    iw = fmaxf(iw, 0.0f);
                    float ih = fminf(qi.w, qj.w) - fmaxf(qi.y, qj.y) + 1.0f;
                    ih = fmaxf(ih, 0.0f);
                    float d = iw * ih;
                    bits |= (d >= bs[j]) ? (1u << b) : 0u;
                }
                int gj = c0 + jb;
                uint32_t selfo = (uint32_t)(i - gj);
                if (selfo < 32u) bits &= ~(1u << selfo);     // j == i excluded
                bw[w] = bits;
            }
            if (rowok) {
                // one 16B row-tile write as 2x8B sc1 stores (16B-aligned base):
                // HBM granule amplification 8x -> 2x vs per-word stores (r8 counter)
                uint64_t* bp = (uint64_t*)&mask[(size_t)i * MW + (c0 >> 5)];
                astore64(bp,     ((uint64_t)bw[1] << 32) | bw[0]);
                astore64(bp + 1, ((uint64_t)bw[3] << 32) | bw[2]);
            }
        }
    }
    flagBarrier(4);
    if (bid != 0) return;

    // ---- phase 6: serial active scan, 256-row chunks (block 0, plain reads) ----
    {
        uint32_t* rem  = (uint32_t*)smem;                // 192
        uint32_t* sidx = rem + 192;                      // 256
        uint32_t* svL  = sidx + CH;                      // 192
        uint32_t* pref = svL + 192;                      // 188
        uint32_t* nsSh = pref + MW;                      // 1
        // restore module-global invariant for the next replay
        if (tid < 16) {
            #pragma unroll
            for (int q = 0; q < 16; q++) g_hist[tid * 16 + q] = 0u;
        }
        if (tid == 16) g_cnt = 0u;
        if (tid < 192) { rem[tid] = 0u; svL[tid] = 0u; }
        for (int i = tid; i < K_POST * 4; i += 256) out[i] = 0.0f;
        __syncthreads();
        uint4 s00 = make_uint4(0,0,0,0), s01 = s00, s10 = s00, s11 = s00;
        uint4 s20 = s00, s21 = s00, s30 = s00, s31 = s00;
        if (tid < 64) {                      // chunk-0 row segments
            const uint32_t* p0 = mask + (size_t)(tid) * MW;
            s00 = *(const uint4*)p0;       s01 = *(const uint4*)(p0 + 4);
            const uint32_t* p1 = mask + (size_t)(64 + tid) * MW;
            s10 = *(const uint4*)p1;       s11 = *(const uint4*)(p1 + 4);
            const uint32_t* p2 = mask + (size_t)(128 + tid) * MW;
            s20 = *(const uint4*)p2;       s21 = *(const uint4*)(p2 + 4);
            const uint32_t* p3 = mask + (size_t)(192 + tid) * MW;
            s30 = *(const uint4*)p3;       s31 = *(const uint4*)(p3 + 4);
        }
        for (int c = 0; c < NCH; c++) {
            int base = c * CH;
            if (tid < 64) {
                uint64_t w0 = ~(((uint64_t)rem[8*c+1] << 32) | (uint64_t)rem[8*c+0]);
                uint64_t w1 = ~(((uint64_t)rem[8*c+3] << 32) | (uint64_t)rem[8*c+2]);
                uint64_t w2 = ~(((uint64_t)rem[8*c+5] << 32) | (uint64_t)rem[8*c+4]);
                uint64_t w3 = ~(((uint64_t)rem[8*c+7] << 32) | (uint64_t)rem[8*c+6]);
                int rows = K_PRE - base;                 // >=256 except last (112)
                if (rows < CH) {
                    auto msk = [](int v) -> uint64_t {
                        return v <= 0 ? 0ull : (v >= 64 ? ~0ull : ((1ull << v) - 1ull));
                    };
                    w0 &= msk(rows); w1 &= msk(rows - 64);
                    w2 &= msk(rows - 128); w3 &= msk(rows - 192);
                }
                uint64_t sv0 = 0ull, sv1 = 0ull, sv2 = 0ull, sv3 = 0ull;
                while (w0 | w1 | w2 | w3) {              // one iter per survivor
                    int k;
                    uint32_t a0, a1, a2, a3, a4, a5, a6, a7;
                    if (w0) {
                        k = __ffsll((unsigned long long)w0) - 1;
                        sv0 |= 1ull << k; w0 &= ~(1ull << k);
                        a0 = (uint32_t)__builtin_amdgcn_readlane((int)s00.x, k);
                        a1 = (uint32_t)__builtin_amdgcn_readlane((int)s00.y, k);
                        a2 = (uint32_t)__builtin_amdgcn_readlane((int)s00.z, k);
                        a3 = (uint32_t)__builtin_amdgcn_readlane((int)s00.w, k);
                        a4 = (uint32_t)__builtin_amdgcn_readlane((int)s01.x, k);
                        a5 = (uint32_t)__builtin_amdgcn_readlane((int)s01.y, k);
                        a6 = (uint32_t)__builtin_amdgcn_readlane((int)s01.z, k);
                        a7 = (uint32_t)__builtin_amdgcn_readlane((int)s01.w, k);
                    } else if (w1) {
                        k = __ffsll((unsigned long long)w1) - 1;
                        sv1 |= 1ull << k; w1 &= ~(1ull << k);
                        a0 = (uint32_t)__builtin_amdgcn_readlane((int)s10.x, k);
                        a1 = (uint32_t)__builtin_amdgcn_readlane((int)s10.y, k);
                        a2 = (uint32_t)__builtin_amdgcn_readlane((int)s10.z, k);
                        a3 = (uint32_t)__builtin_amdgcn_readlane((int)s10.w, k);
                        a4 = (uint32_t)__builtin_amdgcn_readlane((int)s11.x, k);
                        a5 = (uint32_t)__builtin_amdgcn_readlane((int)s11.y, k);
                        a6 = (uint32_t)__builtin_amdgcn_readlane((int)s11.z, k);
                        a7 = (uint32_t)__builtin_amdgcn_readlane((int)s11.w, k);
                    } else if (w2) {
                        k = __ffsll((unsigned long long)w2) - 1;
                        sv2 |= 1ull << k; w2 &= ~(1ull << k);
                        a0 = (uint32_t)__builtin_amdgcn_readlane((int)s20.x, k);
                        a1 = (uint32_t)__builtin_amdgcn_readlane((int)s20.y, k);
                        a2 = (uint32_t)__builtin_amdgcn_readlane((int)s20.z, k);
                        a3 = (uint32_t)__builtin_amdgcn_readlane((int)s20.w, k);
                        a4 = (uint32_t)__builtin_amdgcn_readlane((int)s21.x, k);
                        a5 = (uint32_t)__builtin_amdgcn_readlane((int)s21.y, k);
                        a6 = (uint32_t)__builtin_amdgcn_readlane((int)s21.z, k);
                        a7 = (uint32_t)__builtin_amdgcn_readlane((int)s21.w, k);
                    } else {
                        k = __ffsll((unsigned long long)w3) - 1;
                        sv3 |= 1ull << k; w3 &= ~(1ull << k);
                        a0 = (uint32_t)__builtin_amdgcn_readlane((int)s30.x, k);
                        a1 = (uint32_t)__builtin_amdgcn_readlane((int)s30.y, k);
                        a2 = (uint32_t)__builtin_amdgcn_readlane((int)s30.z, k);
                        a3 = (uint32_t)__builtin_amdgcn_readlane((int)s30.w, k);
                        a4 = (uint32_t)__builtin_amdgcn_readlane((int)s31.x, k);
                        a5 = (uint32_t)__builtin_amdgcn_readlane((int)s31.y, k);
                        a6 = (uint32_t)__builtin_amdgcn_readlane((int)s31.z, k);
                        a7 = (uint32_t)__builtin_amdgcn_readlane((int)s31.w, k);
                    }
                    w0 &= ~(((uint64_t)a1 << 32) | (uint64_t)a0);   // forward kills
                    w1 &= ~(((uint64_t)a3 << 32) | (uint64_t)a2);
                    w2 &= ~(((uint64_t)a5 << 32) | (uint64_t)a4);
                    w3 &= ~(((uint64_t)a7 << 32) | (uint64_t)a6);
                }
                uint32_t n0 = (uint32_t)__popcll(sv0), n1 = (uint32_t)__popcll(sv1);
                uint32_t n2 = (uint32_t)__popcll(sv2), n3 = (uint32_t)__popcll(sv3);
                uint32_t o1 = n0, o2 = n0 + n1, o3 = n0 + n1 + n2, ns = o3 + n3;
                if (tid == 0) {
                    svL[8*c+0] = (uint32_t)sv0; svL[8*c+1] = (uint32_t)(sv0 >> 32);
                    svL[8*c+2] = (uint32_t)sv1; svL[8*c+3] = (uint32_t)(sv1 >> 32);
                    svL[8*c+4] = (uint32_t)sv2; svL[8*c+5] = (uint32_t)(sv2 >> 32);
                    svL[8*c+6] = (uint32_t)sv3; svL[8*c+7] = (uint32_t)(sv3 >> 32);
                    nsSh[0] = ns;
                }
                uint64_t lowm = (1ull << tid) - 1ull;    // tid < 64
                if ((sv0 >> tid) & 1ull) sidx[      __popcll(sv0 & lowm)] = (uint32_t)(base + tid);
                if ((sv1 >> tid) & 1ull) sidx[o1 +  __popcll(sv1 & lowm)] = (uint32_t)(base + 64 + tid);
                if ((sv2 >> tid) & 1ull) sidx[o2 +  __popcll(sv2 & lowm)] = (uint32_t)(base + 128 + tid);
                if ((sv3 >> tid) & 1ull) sidx[o3 +  __popcll(sv3 & lowm)] = (uint32_t)(base + 192 + tid);
                if (ns) {               // pad to x32 with first survivor (OR-idempotent)
                    uint32_t nsPad = (ns + 31u) & ~31u;  // <= 256
                    uint32_t first;
                    if      (sv0) first = (uint32_t)base +       (uint32_t)(__ffsll((unsigned long long)sv0) - 1);
                    else if (sv1) first = (uint32_t)base + 64u + (uint32_t)(__ffsll((unsigned long long)sv1) - 1);
                    else if (sv2) first = (uint32_t)base + 128u+ (uint32_t)(__ffsll((unsigned long long)sv2) - 1);
                    else          first = (uint32_t)base + 192u+ (uint32_t)(__ffsll((unsigned long long)sv3) - 1);
                    #pragma unroll
                    for (int rr = 0; rr < 4; rr++) {
                        uint32_t ii = (uint32_t)tid + 64u * rr;
                        if (ii >= ns && ii < nsPad) sidx[ii] = first;
                    }
                }
                if (c + 1 < NCH) {      // prefetch next chunk rows (overlaps OR phase)
                    const uint32_t* p0 = mask + (size_t)(base + 256 + tid) * MW + 8*(c+1);
                    s00 = *(const uint4*)p0;  s01 = *(const uint4*)(p0 + 4);
                    const uint32_t* p1 = p0 + (size_t)64 * MW;
                    s10 = *(const uint4*)p1;  s11 = *(const uint4*)(p1 + 4);
                    const uint32_t* p2 = p1 + (size_t)64 * MW;
                    s20 = *(const uint4*)p2;  s21 = *(const uint4*)(p2 + 4);
                    const uint32_t* p3 = p2 + (size_t)64 * MW;
                    s30 = *(const uint4*)p3;  s31 = *(const uint4*)(p3 + 4);
                }
            }
            __syncthreads();
            int w = tid - 64;
            if (w >= 0 && w < MW) {
                uint32_t nsPad = (nsSh[0] + 31u) & ~31u;
                uint32_t acc = rem[w];
                for (uint32_t t2 = 0; t2 < nsPad; t2 += 32) {
                    uint32_t r[32];
                    #pragma unroll
                    for (int q = 0; q < 32; q++)
                        r[q] = mask[(size_t)sidx[t2 + q] * MW + w];
                    uint32_t o = 0u;
                    #pragma unroll
                    for (int q = 0; q < 32; q++) o |= r[q];
                    acc |= o;
                }
                rem[w] = acc;
            }
            __syncthreads();
        }
        // final validity + emit first 300 (tail already zeroed above)
        if (tid < MW) {
            uint32_t vv = svL[tid] & ~rem[tid];
            if (tid == MW - 1) vv &= 0xFFFFu;
            rem[tid] = vv;
        }
        __syncthreads();
        if (tid == 0) {
            uint32_t run = 0;
            for (int w2 = 0; w2 < MW; w2++) { pref[w2] = run; run += (uint32_t)__popc(rem[w2]); }
        }
        __syncthreads();
        if (tid < MW) {
            uint32_t b = rem[tid];
            uint32_t r = pref[tid];
            int basebit = tid * 32;
            while (b && r < K_POST) {
                int bit = __ffs(b) - 1;
                b &= b - 1u;
                float4 pp = OP[basebit + bit];
                *(float4*)(out + (size_t)r * 4) = pp;
                r++;
            }
        }
    }
}

extern "C" void kernel_launch(void* const* d_in, const int* in_sizes, int n_in,
                              void* d_out, int out_size, void* d_ws, size_t ws_size,
                              hipStream_t stream) {
    (void)in_sizes; (void)n_in; (void)out_size; (void)ws_size;
    const float* scores = (const float*)d_in[0];
    const float* deltas = (const float*)d_in[1];
    float* out = (float*)d_out;
    char* ws = (char*)d_ws;
    mega<<<NBLK, 256, 0, stream>>>(scores, deltas, out, ws);
}

// Round 10
// 154.870 us; speedup vs baseline: 2.6159x; 1.0289x over previous
//
#include <hip/hip_runtime.h>
#include <cstdint>
#include <cstddef>

#define N_TOT   147456      // 9*128*128
#define K_PRE   6000
#define K_POST  300
#define CAP     32768       // candidate cap (expected ~9.2K)
#define MW      188         // 6016 bits per mask row -> 188 u32 words
#define ROWS_PAD 6144       // 24*256 (scan prefetch range)
#define CH      256         // scan rows per chunk
#define NCH     24          // 24*256 = 6144
#define CT      128         // mask columns per tile
#define ROWB    24
#define COLB    47          // ceil(6000/128)
#define NTILE   (ROWB*COLB) // 1128 mask tiles
#define G       16          // candidates ranked per block
#define NBLK    576         // __launch_bounds__(256,4) => 1024 capacity, all resident
#define HBLK    144         // work blocks for hist/findbin (4 anchors/thread)
#define GSZ     24          // barrier tree group size

// workspace offsets (256-aligned); keys live in registers across phases 1->2.
#define OFF_CAND 0u
#define OFF_P    262144u
#define OFF_YK   358144u
#define OFF_OP   406272u
#define OFF_Q    502272u
#define OFF_BND  598272u
#define OFF_MASK 622336u    // + ROWS_PAD*MW*4 + 256 slack

__constant__ float c_sizes[9] = {4.f,8.f,12.f,16.f,24.f,32.f,48.f,64.f,96.f};

// Zero-initialized module globals. g_hist/g_cnt re-zeroed by k_scan each run.
// Barrier counters/releases are MONOTONIC (never reset) -> replay-safe.
__device__ uint32_t g_hist[4096];
__device__ uint32_t g_cnt;
__device__ uint32_t g_barL[4][GSZ * 16];    // leaf arrival counters (<=24 groups), 64B-padded
__device__ uint32_t g_barR[4 * 16];         // root counters, 64B-padded
__device__ uint32_t g_rel[4][GSZ * 16];     // per-group release flags, 64B-padded

// ---- coherence model (validated r7-r9: absmax=0 across 3 rounds) ----
// Data crossing an INTERNAL barrier: sc1 (agent-scope) writes -> coherence
// point; readers use PLAIN loads after the barrier (no XCD holds a stale
// line: region never plain-touched before its sc1 writes; L2s invalidated at
// kernel launch). Data crossing a KERNEL boundary (mask, OP, globals): plain
// writes -- the runtime's end-of-kernel flush provides coherence for free.
__device__ __forceinline__ void astore32(uint32_t* p, uint32_t v) {
    __hip_atomic_store(p, v, __ATOMIC_RELAXED, __HIP_MEMORY_SCOPE_AGENT);
}
__device__ __forceinline__ void astore64(uint64_t* p, uint64_t v) {
    __hip_atomic_store(p, v, __ATOMIC_RELAXED, __HIP_MEMORY_SCOPE_AGENT);
}
__device__ __forceinline__ void astoreF4(float4* p, float4 v) {
    union { float4 f; uint64_t u[2]; } c; c.f = v;
    astore64((uint64_t*)p, c.u[0]);
    astore64(((uint64_t*)p) + 1, c.u[1]);
}

// 2-level tree barrier with broadcast release (r8: arrival tree -68us vs flat;
// r9: split release lines). nprt = participating blocks (0..nprt-1), must be
// a multiple of GSZ. Monotonic counters -> replay-safe.
__device__ __forceinline__ void treeBarrier(int i, int nprt) {
    __syncthreads();   // drains vmcnt: this block's sc1 stores are at the
                       // coherence point before its ticket lands (r7 model)
    if (threadIdx.x == 0) {
        int ngrp = nprt / GSZ;
        int grp  = (int)(blockIdx.x / GSZ);
        int mem  = (int)(blockIdx.x % GSZ);
        uint32_t t = __hip_atomic_fetch_add(&g_barL[i][grp * 16], 1u,
                          __ATOMIC_RELAXED, __HIP_MEMORY_SCOPE_AGENT);
        uint32_t round = t / GSZ;
        if ((t % GSZ) == GSZ - 1u)                  // group complete -> root
            __hip_atomic_fetch_add(&g_barR[i * 16], 1u,
                __ATOMIC_RELAXED, __HIP_MEMORY_SCOPE_AGENT);
        uint32_t tries = 0;
        if (mem == 0) {                             // leader: poll root, release group
            uint32_t target = (round + 1u) * (uint32_t)ngrp;
            while (__hip_atomic_load(&g_barR[i * 16], __ATOMIC_RELAXED,
                                     __HIP_MEMORY_SCOPE_AGENT) < target) {
                __builtin_amdgcn_s_sleep(2);
                if (++tries > (1u << 20)) break;    // fail loud, not hung
            }
            astore32(&g_rel[i][grp * 16], round + 1u);
        } else {                                    // member: poll group release
            while (__hip_atomic_load(&g_rel[i][grp * 16], __ATOMIC_RELAXED,
                                     __HIP_MEMORY_SCOPE_AGENT) < round + 1u) {
                __builtin_amdgcn_s_sleep(2);
                if (++tries > (1u << 20)) break;
            }
        }
        asm volatile("" ::: "memory");
    }
    __syncthreads();
}

// Bit-exact replication of reference box math (anchor + delta, clip).
__device__ __forceinline__ void compute_box(int idx, const float* __restrict__ deltas,
                                            float& px1, float& py1, float& pw, float& ph) {
    int a   = idx >> 14;
    int rem = idx & 16383;
    int h   = rem >> 7;
    int w   = rem & 127;
    float s    = c_sizes[a];
    float half = s * 0.5f;
    const float4 d = *(const float4*)(deltas + (size_t)a * 65536 + (size_t)rem * 4);
    float b0 = (((float)h + 0.5f) - half) + d.x;
    float b1 = (((float)w + 0.5f) - half) + d.y;
    float b2 = s + d.z;
    float b3 = s + d.w;
    b0 = fmaxf(b0, 0.0f); b1 = fmaxf(b1, 0.0f);
    b2 = fmaxf(b2, 0.0f); b3 = fmaxf(b3, 0.0f);
    float x1 = b0, y1 = b1;
    float x2 = b0 + b2, y2 = b1 + b3;
    x1 = fminf(x1, 128.0f); y1 = fminf(y1, 128.0f);
    x2 = fminf(x2, 128.0f); y2 = fminf(y2, 128.0f);
    px1 = x1; py1 = y1; pw = x2 - x1; ph = y2 - y1;
}

__device__ __forceinline__ uint32_t waveReduceSum(uint32_t v) {
    #pragma unroll
    for (int o = 32; o > 0; o >>= 1) v += __shfl_xor(v, o, 64);
    return v;
}

// ============================================================================
// K_A: phases 1-5 fused, 4 internal tree barriers. Mask/OP written PLAIN
// (cross-kernel data -> runtime end-of-kernel flush gives coherence free).
// ============================================================================
__global__ void __launch_bounds__(256, 4) fusedA(const float* __restrict__ scores,
                                                 const float* __restrict__ deltas,
                                                 char* __restrict__ ws) {
    __shared__ __align__(16) char smem[17664];

    uint64_t* cand = (uint64_t*)(ws + OFF_CAND);
    float4*   P    = (float4*)(ws + OFF_P);
    uint64_t* yk   = (uint64_t*)(ws + OFF_YK);
    float4*   OP   = (float4*)(ws + OFF_OP);
    float4*   Q    = (float4*)(ws + OFF_Q);
    float*    Bnd  = (float*)(ws + OFF_BND);
    uint32_t* mask = (uint32_t*)(ws + OFF_MASK);

    const int tid  = threadIdx.x;
    const int bid  = blockIdx.x;
    const int wave = tid >> 6, lane = tid & 63;

    // ---- phases 1+2: only blocks 0..143 participate; barrier 0 is 144-wide ----
    if (bid < HBLK) {
        uint32_t k4x, k4y, k4z, k4w;               // keys in registers across 1->2
        {   // phase 1: keys + histogram (4 anchors/thread)
            uint32_t* lh = (uint32_t*)smem;
            for (int i = tid; i < 4096; i += 256) lh[i] = 0u;
            __syncthreads();
            int t4 = (bid * 256 + tid) * 4;
            float4 sc4 = *(const float4*)(scores + t4);
            uint32_t k4[4];
            #pragma unroll
            for (int e = 0; e < 4; e++) {
                int idx = t4 + e;
                float px1, py1, pw, ph;
                compute_box(idx, deltas, px1, py1, pw, ph);
                bool keep = (pw >= 3.0f) && (ph >= 3.0f);
                float sc = (&sc4.x)[e];
                uint32_t key = keep ? __float_as_uint(sc) : 0u;
                k4[e] = key;
                atomicAdd(&lh[key >> 20], 1u);
            }
            k4x = k4[0]; k4y = k4[1]; k4z = k4[2]; k4w = k4[3];
            __syncthreads();
            for (int i = tid; i < 4096; i += 256) {
                uint32_t v = lh[i];
                if (v) atomicAdd(&g_hist[i], v);     // device-scope RMW
            }
        }
        treeBarrier(0, HBLK);                        // 144-wide (6 groups)
        {   // phase 2: findbin (suffix scan) + block-ticket compact
            uint32_t* lh   = (uint32_t*)smem;
            uint32_t* seg  = (uint32_t*)(smem + 16384);
            uint32_t* bshp = (uint32_t*)(smem + 16384 + 1024);
            uint32_t* lcnt = bshp + 1;
            uint32_t* lbas = bshp + 2;
            if (tid == 0) lcnt[0] = 0u;
            for (int i = tid; i < 4096; i += 256) lh[i] = g_hist[i];   // plain post-barrier
            __syncthreads();
            uint32_t s = 0;
            #pragma unroll
            for (int q = 0; q < 16; q++) s += lh[tid * 16 + q];
            seg[tid] = s;
            __syncthreads();
            for (int off = 1; off < 256; off <<= 1) {
                uint32_t v = seg[tid];
                if (tid + off < 256) v += seg[tid + off];
                __syncthreads();
                seg[tid] = v;
                __syncthreads();
            }
            uint32_t St  = seg[tid];
            uint32_t St1 = (tid < 255) ? seg[tid + 1] : 0u;
            if (St >= K_PRE && St1 < K_PRE) {
                uint32_t c2 = St1;
                uint32_t bstar = 0u;
                for (int q = 15; q >= 0; q--) {
                    c2 += lh[tid * 16 + q];
                    if (c2 >= K_PRE) { bstar = (uint32_t)(tid * 16 + q); break; }
                }
                bshp[0] = bstar;
            }
            if (tid == 0 && seg[0] < K_PRE) bshp[0] = 0u;
            __syncthreads();
            uint32_t bstar = bshp[0];
            int t4 = (bid * 256 + tid) * 4;
            bool s0 = (k4x >> 20) >= bstar;
            bool s1 = (k4y >> 20) >= bstar;
            bool s2 = (k4z >> 20) >= bstar;
            bool s3 = (k4w >> 20) >= bstar;
            uint32_t nsel = (uint32_t)s0 + s1 + s2 + s3;
            uint32_t myoff = 0u;
            if (nsel) myoff = atomicAdd(lcnt, nsel);
            __syncthreads();
            if (tid == 0) lbas[0] = atomicAdd(&g_cnt, lcnt[0]);
            __syncthreads();
            uint32_t pos = lbas[0] + myoff;
            if (s0) { if (pos < CAP) astore64(&cand[pos], ((uint64_t)k4x << 32) | (uint32_t)(~(uint32_t)(t4 + 0))); pos++; }
            if (s1) { if (pos < CAP) astore64(&cand[pos], ((uint64_t)k4y << 32) | (uint32_t)(~(uint32_t)(t4 + 1))); pos++; }
            if (s2) { if (pos < CAP) astore64(&cand[pos], ((uint64_t)k4z << 32) | (uint32_t)(~(uint32_t)(t4 + 2))); pos++; }
            if (s3) { if (pos < CAP) astore64(&cand[pos], ((uint64_t)k4w << 32) | (uint32_t)(~(uint32_t)(t4 + 3))); }
        }
    }
    treeBarrier(1, NBLK);

    // ---- phase 3: rank-by-count over candidates -> P, yk (plain cand reads) ----
    {
        uint32_t (*part)[G] = (uint32_t (*)[G])smem;
        uint32_t C = g_cnt;                     // plain post-barrier
        if (C > CAP) C = CAP;
        uint32_t nGroups = (C + G - 1) / G;     // ~575 <= NBLK
        for (uint32_t g = bid; g < nGroups; g += NBLK) {
            uint32_t b = g * G;
            uint64_t m[G];
            uint32_t cnt[G];
            #pragma unroll
            for (int q = 0; q < G; q++) {
                m[q] = (b + q < C) ? cand[b + q] : ~0ull;
                cnt[q] = 0u;
            }
            for (uint32_t j0 = 0; j0 < C; j0 += 1024) {
                uint32_t ja = j0 + tid, jb = ja + 256, jc = ja + 512, jd = ja + 768;
                uint64_t ka = (ja < C) ? cand[ja] : 0ull;   // plain: L2-cached re-reads
                uint64_t kb = (jb < C) ? cand[jb] : 0ull;
                uint64_t kc = (jc < C) ? cand[jc] : 0ull;
                uint64_t kd = (jd < C) ? cand[jd] : 0ull;
                #pragma unroll
                for (int q = 0; q < G; q++)
                    cnt[q] += (uint32_t)(ka > m[q]) + (uint32_t)(kb > m[q])
                            + (uint32_t)(kc > m[q]) + (uint32_t)(kd > m[q]);
            }
            #pragma unroll
            for (int q = 0; q < G; q++) cnt[q] = waveReduceSum(cnt[q]);
            if (lane == 0) {
                #pragma unroll
                for (int q = 0; q < G; q++) part[wave][q] = cnt[q];
            }
            __syncthreads();
            if (tid < G && b + tid < C) {
                uint32_t r = part[0][tid] + part[1][tid] + part[2][tid] + part[3][tid];
                if (r < K_PRE) {
                    int idx = (int)(~((uint32_t)cand[b + tid]));
                    float px1, py1, pw, ph;
                    compute_box(idx, deltas, px1, py1, pw, ph);
                    astoreF4(&P[r], make_float4(px1, py1, pw, ph));
                    float y2 = py1 + ph;
                    astore64(&yk[r], ((uint64_t)__float_as_uint(y2) << 32) | (uint32_t)(~r));
                }
            }
            __syncthreads();
        }
    }
    treeBarrier(2, NBLK);

    // ---- phase 4: stable y2-desc rank + epilogue (plain yk/P reads) ----
    if (bid < K_PRE / G) {
        uint32_t (*part)[G] = (uint32_t (*)[G])smem;
        uint32_t b = (uint32_t)bid * G;
        uint64_t m[G];
        uint32_t cnt[G];
        #pragma unroll
        for (int q = 0; q < G; q++) {
            m[q] = yk[b + q];
            cnt[q] = 0u;
        }
        for (uint32_t j0 = 0; j0 < K_PRE; j0 += 1024) {
            uint32_t ja = j0 + tid, jb = ja + 256, jc = ja + 512, jd = ja + 768;
            uint64_t ka = (ja < K_PRE) ? yk[ja] : 0ull;
            uint64_t kb = (jb < K_PRE) ? yk[jb] : 0ull;
            uint64_t kc = (jc < K_PRE) ? yk[jc] : 0ull;
            uint64_t kd = (jd < K_PRE) ? yk[jd] : 0ull;
            #pragma unroll
            for (int q = 0; q < G; q++)
                cnt[q] += (uint32_t)(ka > m[q]) + (uint32_t)(kb > m[q])
                        + (uint32_t)(kc > m[q]) + (uint32_t)(kd > m[q]);
        }
        #pragma unroll
        for (int q = 0; q < G; q++) cnt[q] = waveReduceSum(cnt[q]);
        if (lane == 0) {
            #pragma unroll
            for (int q = 0; q < G; q++) part[wave][q] = cnt[q];
        }
        __syncthreads();
        if (tid < G) {
            uint32_t r = part[0][tid] + part[1][tid] + part[2][tid] + part[3][tid];
            float4 p = P[b + tid];
            OP[r] = p;                  // plain: consumed by k_scan (next kernel)
            float x1 = p.x, y1 = p.y;
            float x2 = x1 + p.z, y2 = y1 + p.w;
            float area = fmaxf((x2 - x1) * (y2 - y1), 1e-6f);
            astoreF4(&Q[r], make_float4(x1, y1, x2, y2));    // crosses barrier 3
            const double Mc = (double)0.7f - 0x1.0p-25;
            double c = Mc * (double)area;       // exact
            float Bf = (float)c;
            if (!((double)Bf > c)) Bf = __int_as_float(__float_as_int(Bf) + 1);
            astore32((uint32_t*)&Bnd[r], __float_as_uint(Bf));
        }
    }
    treeBarrier(3, NBLK);

    // ---- phase 5: suppression bitmask (plain Q/Bnd reads, PLAIN 16B writes) ----
    {
        float4* qs = (float4*)smem;
        float*  bs = (float*)(smem + CT * 16);
        for (uint32_t t = bid; t < NTILE; t += NBLK) {
            int bx = (int)(t % ROWB);
            int by = (int)(t / ROWB);
            int i  = bx * 256 + tid;
            int c0 = by * CT;
            int ncols = min(CT, K_PRE - c0);        // 128 or 112 (last col tile)
            bool rowok = (i < K_PRE);
            float4 qi = rowok ? Q[i] : make_float4(0.f, 0.f, 0.f, 0.f);
            __syncthreads();     // protect qs/bs from previous iteration's readers
            for (int j = tid; j < ncols; j += 256) {
                qs[j] = Q[c0 + j];
                bs[j] = Bnd[c0 + j];
            }
            __syncthreads();
            uint32_t bw[4];
            #pragma unroll
            for (int w = 0; w < 4; w++) {
                uint32_t bits = 0u;
                int jb = w * 32;
                int jn = min(32, ncols - jb);       // >=16 always
                #pragma unroll 8
                for (int b = 0; b < jn; b++) {
                    int j = jb + b;
                    float4 qj = qs[j];
                    float iw = fminf(qi.z, qj.z) - fmaxf(qi.x, qj.x) + 1.0f;
                    iw = fmaxf(iw, 0.0f);
                    float ih = fminf(qi.w, qj.w) - fmaxf(qi.y, qj.y) + 1.0f;
                    ih = fmaxf(ih, 0.0f);
                    float d = iw * ih;
                    bits |= (d >= bs[j]) ? (1u << b) : 0u;
                }
                int gj = c0 + jb;
                uint32_t selfo = (uint32_t)(i - gj);
                if (selfo < 32u) bits &= ~(1u << selfo);     // j == i excluded
                bw[w] = bits;
            }
            if (rowok) {
                // plain 16B write-back store (row base 752B = 16B-aligned;
                // word idx multiple of 4): L2 coalesces, no WT amplification
                *(uint4*)&mask[(size_t)i * MW + (c0 >> 5)] =
                    make_uint4(bw[0], bw[1], bw[2], bw[3]);
            }
        }
    }
    // kernel end: runtime flush makes mask/OP visible to k_scan (free coherence)
}

// ============================================================================
// K_B: serial active scan, 256-row chunks (verified r5 structure, plain reads).
// Re-zeros g_hist/g_cnt for the next replay.
// ============================================================================
__global__ void __launch_bounds__(256) k_scan(const uint32_t* __restrict__ mask,
                                              const float4* __restrict__ OP,
                                              float* __restrict__ out) {
    __shared__ uint32_t rem[192];        // 24*8; words >= MW unused in epilogue
    __shared__ uint32_t sidx[CH];
    __shared__ uint32_t svL[192];
    __shared__ uint32_t nsSh;
    __shared__ uint32_t pref[MW];
    int tid = threadIdx.x;
    // restore module-global invariant for the next replay
    if (tid < 16) {
        #pragma unroll
        for (int q = 0; q < 16; q++) g_hist[tid * 16 + q] = 0u;
    }
    if (tid == 16) g_cnt = 0u;
    if (tid < 192) { rem[tid] = 0u; svL[tid] = 0u; }
    for (int i = tid; i < K_POST * 4; i += 256) out[i] = 0.0f;
    __syncthreads();
    uint4 s00 = make_uint4(0,0,0,0), s01 = s00, s10 = s00, s11 = s00;
    uint4 s20 = s00, s21 = s00, s30 = s00, s31 = s00;
    if (tid < 64) {                      // chunk-0 row segments
        const uint32_t* p0 = mask + (size_t)(tid) * MW;
        s00 = *(const uint4*)p0;       s01 = *(const uint4*)(p0 + 4);
        const uint32_t* p1 = mask + (size_t)(64 + tid) * MW;
        s10 = *(const uint4*)p1;       s11 = *(const uint4*)(p1 + 4);
        const uint32_t* p2 = mask + (size_t)(128 + tid) * MW;
        s20 = *(const uint4*)p2;       s21 = *(const uint4*)(p2 + 4);
        const uint32_t* p3 = mask + (size_t)(192 + tid) * MW;
        s30 = *(const uint4*)p3;       s31 = *(const uint4*)(p3 + 4);
    }
    for (int c = 0; c < NCH; c++) {
        int base = c * CH;
        if (tid < 64) {
            uint64_t w0 = ~(((uint64_t)rem[8*c+1] << 32) | (uint64_t)rem[8*c+0]);
            uint64_t w1 = ~(((uint64_t)rem[8*c+3] << 32) | (uint64_t)rem[8*c+2]);
            uint64_t w2 = ~(((uint64_t)rem[8*c+5] << 32) | (uint64_t)rem[8*c+4]);
            uint64_t w3 = ~(((uint64_t)rem[8*c+7] << 32) | (uint64_t)rem[8*c+6]);
            int rows = K_PRE - base;                 // >=256 except last (112)
            if (rows < CH) {
                auto msk = [](int v) -> uint64_t {
                    return v <= 0 ? 0ull : (v >= 64 ? ~0ull : ((1ull << v) - 1ull));
                };
                w0 &= msk(rows); w1 &= msk(rows - 64);
                w2 &= msk(rows - 128); w3 &= msk(rows - 192);
            }
            uint64_t sv0 = 0ull, sv1 = 0ull, sv2 = 0ull, sv3 = 0ull;
            while (w0 | w1 | w2 | w3) {              // one iter per survivor
                int k;
                uint32_t a0, a1, a2, a3, a4, a5, a6, a7;
                if (w0) {
                    k = __ffsll((unsigned long long)w0) - 1;
                    sv0 |= 1ull << k; w0 &= ~(1ull << k);
                    a0 = (uint32_t)__builtin_amdgcn_readlane((int)s00.x, k);
                    a1 = (uint32_t)__builtin_amdgcn_readlane((int)s00.y, k);
                    a2 = (uint32_t)__builtin_amdgcn_readlane((int)s00.z, k);
                    a3 = (uint32_t)__builtin_amdgcn_readlane((int)s00.w, k);
                    a4 = (uint32_t)__builtin_amdgcn_readlane((int)s01.x, k);
                    a5 = (uint32_t)__builtin_amdgcn_readlane((int)s01.y, k);
                    a6 = (uint32_t)__builtin_amdgcn_readlane((int)s01.z, k);
                    a7 = (uint32_t)__builtin_amdgcn_readlane((int)s01.w, k);
                } else if (w1) {
                    k = __ffsll((unsigned long long)w1) - 1;
                    sv1 |= 1ull << k; w1 &= ~(1ull << k);
                    a0 = (uint32_t)__builtin_amdgcn_readlane((int)s10.x, k);
                    a1 = (uint32_t)__builtin_amdgcn_readlane((int)s10.y, k);
                    a2 = (uint32_t)__builtin_amdgcn_readlane((int)s10.z, k);
                    a3 = (uint32_t)__builtin_amdgcn_readlane((int)s10.w, k);
                    a4 = (uint32_t)__builtin_amdgcn_readlane((int)s11.x, k);
                    a5 = (uint32_t)__builtin_amdgcn_readlane((int)s11.y, k);
                    a6 = (uint32_t)__builtin_amdgcn_readlane((int)s11.z, k);
                    a7 = (uint32_t)__builtin_amdgcn_readlane((int)s11.w, k);
                } else if (w2) {
                    k = __ffsll((unsigned long long)w2) - 1;
                    sv2 |= 1ull << k; w2 &= ~(1ull << k);
                    a0 = (uint32_t)__builtin_amdgcn_readlane((int)s20.x, k);
                    a1 = (uint32_t)__builtin_amdgcn_readlane((int)s20.y, k);
                    a2 = (uint32_t)__builtin_amdgcn_readlane((int)s20.z, k);
                    a3 = (uint32_t)__builtin_amdgcn_readlane((int)s20.w, k);
                    a4 = (uint32_t)__builtin_amdgcn_readlane((int)s21.x, k);
                    a5 = (uint32_t)__builtin_amdgcn_readlane((int)s21.y, k);
                    a6 = (uint32_t)__builtin_amdgcn_readlane((int)s21.z, k);
                    a7 = (uint32_t)__builtin_amdgcn_readlane((int)s21.w, k);
                } else {
                    k = __ffsll((unsigned long long)w3) - 1;
                    sv3 |= 1ull << k; w3 &= ~(1ull << k);
                    a0 = (uint32_t)__builtin_amdgcn_readlane((int)s30.x, k);
                    a1 = (uint32_t)__builtin_amdgcn_readlane((int)s30.y, k);
                    a2 = (uint32_t)__builtin_amdgcn_readlane((int)s30.z, k);
                    a3 = (uint32_t)__builtin_amdgcn_readlane((int)s30.w, k);
                    a4 = (uint32_t)__builtin_amdgcn_readlane((int)s31.x, k);
                    a5 = (uint32_t)__builtin_amdgcn_readlane((int)s31.y, k);
                    a6 = (uint32_t)__builtin_amdgcn_readlane((int)s31.z, k);
                    a7 = (uint32_t)__builtin_amdgcn_readlane((int)s31.w, k);
                }
                w0 &= ~(((uint64_t)a1 << 32) | (uint64_t)a0);   // forward kills
                w1 &= ~(((uint64_t)a3 << 32) | (uint64_t)a2);
                w2 &= ~(((uint64_t)a5 << 32) | (uint64_t)a4);
                w3 &= ~(((uint64_t)a7 << 32) | (uint64_t)a6);
            }
            uint32_t n0 = (uint32_t)__popcll(sv0), n1 = (uint32_t)__popcll(sv1);
            uint32_t n2 = (uint32_t)__popcll(sv2), n3 = (uint32_t)__popcll(sv3);
            uint32_t o1 = n0, o2 = n0 + n1, o3 = n0 + n1 + n2, ns = o3 + n3;
            if (tid == 0) {
                svL[8*c+0] = (uint32_t)sv0; svL[8*c+1] = (uint32_t)(sv0 >> 32);
                svL[8*c+2] = (uint32_t)sv1; svL[8*c+3] = (uint32_t)(sv1 >> 32);
                svL[8*c+4] = (uint32_t)sv2; svL[8*c+5] = (uint32_t)(sv2 >> 32);
                svL[8*c+6] = (uint32_t)sv3; svL[8*c+7] = (uint32_t)(sv3 >> 32);
                nsSh = ns;
            }
            uint64_t lowm = (1ull << tid) - 1ull;    // tid < 64
            if ((sv0 >> tid) & 1ull) sidx[      __popcll(sv0 & lowm)] = (uint32_t)(base + tid);
            if ((sv1 >> tid) & 1ull) sidx[o1 +  __popcll(sv1 & lowm)] = (uint32_t)(base + 64 + tid);
            if ((sv2 >> tid) & 1ull) sidx[o2 +  __popcll(sv2 & lowm)] = (uint32_t)(base + 128 + tid);
            if ((sv3 >> tid) & 1ull) sidx[o3 +  __popcll(sv3 & lowm)] = (uint32_t)(base + 192 + tid);
            if (ns) {                 // pad to x32 with first survivor (OR-idempotent)
                uint32_t nsPad = (ns + 31u) & ~31u;  // <= 256
                uint32_t first;
                if      (sv0) first = (uint32_t)base +       (uint32_t)(__ffsll((unsigned long long)sv0) - 1);
                else if (sv1) first = (uint32_t)base + 64u + (uint32_t)(__ffsll((unsigned long long)sv1) - 1);
                else if (sv2) first = (uint32_t)base + 128u+ (uint32_t)(__ffsll((unsigned long long)sv2) - 1);
                else          first = (uint32_t)base + 192u+ (uint32_t)(__ffsll((unsigned long long)sv3) - 1);
                #pragma unroll
                for (int rr = 0; rr < 4; rr++) {
                    uint32_t ii = (uint32_t)tid + 64u * rr;
                    if (ii >= ns && ii < nsPad) sidx[ii] = first;
                }
            }
            if (c + 1 < NCH) {        // prefetch next chunk rows (overlaps OR phase)
                const uint32_t* p0 = mask + (size_t)(base + 256 + tid) * MW + 8*(c+1);
                s00 = *(const uint4*)p0;  s01 = *(const uint4*)(p0 + 4);
                const uint32_t* p1 = p0 + (size_t)64 * MW;
                s10 = *(const uint4*)p1;  s11 = *(const uint4*)(p1 + 4);
                const uint32_t* p2 = p1 + (size_t)64 * MW;
                s20 = *(const uint4*)p2;  s21 = *(const uint4*)(p2 + 4);
                const uint32_t* p3 = p2 + (size_t)64 * MW;
                s30 = *(const uint4*)p3;  s31 = *(const uint4*)(p3 + 4);
            }
        }
        __syncthreads();
        int w = tid - 64;
        if (w >= 0 && w < MW) {
            uint32_t nsPad = (nsSh + 31u) & ~31u;
            uint32_t acc = rem[w];
            for (uint32_t t2 = 0; t2 < nsPad; t2 += 32) {
                uint32_t r[32];
                #pragma unroll
                for (int q = 0; q < 32; q++)
                    r[q] = mask[(size_t)sidx[t2 + q] * MW + w];
                uint32_t o = 0u;
                #pragma unroll
                for (int q = 0; q < 32; q++) o |= r[q];
                acc |= o;
            }
            rem[w] = acc;
        }
        __syncthreads();
    }
    // final validity + emit first 300 (tail already zeroed above)
    if (tid < MW) {
        uint32_t vv = svL[tid] & ~rem[tid];
        if (tid == MW - 1) vv &= 0xFFFFu;
        rem[tid] = vv;
    }
    __syncthreads();
    if (tid == 0) {
        uint32_t run = 0;
        for (int w2 = 0; w2 < MW; w2++) { pref[w2] = run; run += (uint32_t)__popc(rem[w2]); }
    }
    __syncthreads();
    if (tid < MW) {
        uint32_t b = rem[tid];
        uint32_t r = pref[tid];
        int basebit = tid * 32;
        while (b && r < K_POST) {
            int bit = __ffs(b) - 1;
            b &= b - 1u;
            float4 pp = OP[basebit + bit];
            *(float4*)(out + (size_t)r * 4) = pp;
            r++;
        }
    }
}

extern "C" void kernel_launch(void* const* d_in, const int* in_sizes, int n_in,
                              void* d_out, int out_size, void* d_ws, size_t ws_size,
                              hipStream_t stream) {
    (void)in_sizes; (void)n_in; (void)out_size; (void)ws_size;
    const float* scores = (const float*)d_in[0];
    const float* deltas = (const float*)d_in[1];
    float* out = (float*)d_out;
    char* ws = (char*)d_ws;
    fusedA<<<NBLK, 256, 0, stream>>>(scores, deltas, ws);
    k_scan<<<1, 256, 0, stream>>>((const uint32_t*)(ws + OFF_MASK),
                                  (const float4*)(ws + OFF_OP), out);
}